// Round 22
// baseline (1481.450 us; speedup 1.0000x reference)
//
#include <hip/hip_runtime.h>
#include <cstddef>

// B=2, L=4096, HID=1024, H=16, D=64, C=256, KM_ITERS=10 (11 assign/update rounds)
// BH=32, M=B*L=8192

typedef _Float16 h8 __attribute__((ext_vector_type(8)));
typedef _Float16 h4 __attribute__((ext_vector_type(4)));
typedef float f4 __attribute__((ext_vector_type(4)));

#define MFMA16(a, b, c) __builtin_amdgcn_mfma_f32_16x16x32_f16((a), (b), (c), 0, 0, 0)

// fp32 -> f16 splits. lo scaled by 2^11, quad term by 2^22 (avoids f16 subnormals).
__device__ __forceinline__ void split3(float x, _Float16* h, _Float16* l, _Float16* q) {
  _Float16 hh = (_Float16)x;
  float r1 = x - (float)hh;
  _Float16 ll = (_Float16)(r1 * 2048.0f);
  float r2 = fmaf((float)ll, -4.8828125e-4f, r1);
  *h = hh; *l = ll; *q = (_Float16)(r2 * 4194304.0f);
}
__device__ __forceinline__ void split2(float x, _Float16* h, _Float16* l) {
  _Float16 hh = (_Float16)x;
  float r1 = x - (float)hh;
  *h = hh; *l = (_Float16)(r1 * 2048.0f);
}

// ---------------------------------------------------------------------------
// elementwise split2 of an 8,388,608-float array (X only now).
// ---------------------------------------------------------------------------
__global__ __launch_bounds__(256) void xsplit2_kernel(const float* __restrict__ X,
                                                      _Float16* __restrict__ xh,
                                                      _Float16* __restrict__ xl) {
  size_t i = ((size_t)blockIdx.x * 256 + threadIdx.x) * 4;
  float4 v = *(const float4*)(X + i);
  float xs[4] = {v.x, v.y, v.z, v.w};
  h4 vh, vl;
#pragma unroll
  for (int j = 0; j < 4; ++j) {
    _Float16 a, b;
    split2(xs[j], &a, &b);
    vh[j] = a; vl[j] = b;
  }
  *(h4*)(xh + i) = vh;
  *(h4*)(xl + i) = vl;
}

// ---------------------------------------------------------------------------
// W[1024][1024] -> Wt_h/l/q[n][k] (transposed + split). tq may be null.
// ---------------------------------------------------------------------------
__global__ __launch_bounds__(256) void tsplit_kernel(const float* __restrict__ W,
                                                     _Float16* __restrict__ th,
                                                     _Float16* __restrict__ tl,
                                                     _Float16* __restrict__ tq) {
  __shared__ float tile[32][33];
  const int n0 = blockIdx.x * 32, k0 = blockIdx.y * 32;
  const int tx = threadIdx.x & 31, ty = threadIdx.x >> 5;
#pragma unroll
  for (int i = 0; i < 4; ++i) {
    int k = ty + i * 8;
    tile[k][tx] = W[(size_t)(k0 + k) * 1024 + n0 + tx];
  }
  __syncthreads();
#pragma unroll
  for (int i = 0; i < 4; ++i) {
    int n = ty + i * 8;
    float x = tile[tx][n];
    _Float16 h, l, q;
    split3(x, &h, &l, &q);
    size_t o = (size_t)(n0 + n) * 1024 + k0 + tx;
    th[o] = h; tl[o] = l;
    if (tq) tq[o] = q;
  }
}

// ---------------------------------------------------------------------------
// Fused transpose+split of BOTH Wk and Wv in one launch (r19-proven).
// ---------------------------------------------------------------------------
__global__ __launch_bounds__(256) void tsplit_kv_kernel(const float* __restrict__ Wk,
                                                        const float* __restrict__ Wv,
                                                        _Float16* __restrict__ thk,
                                                        _Float16* __restrict__ tlk,
                                                        _Float16* __restrict__ thv,
                                                        _Float16* __restrict__ tlv) {
  __shared__ float tk[32][33];
  __shared__ float tv[32][33];
  const int n0 = blockIdx.x * 32, k0 = blockIdx.y * 32;
  const int tx = threadIdx.x & 31, ty = threadIdx.x >> 5;
#pragma unroll
  for (int i = 0; i < 4; ++i) {
    int k = ty + i * 8;
    tk[k][tx] = Wk[(size_t)(k0 + k) * 1024 + n0 + tx];
    tv[k][tx] = Wv[(size_t)(k0 + k) * 1024 + n0 + tx];
  }
  __syncthreads();
#pragma unroll
  for (int i = 0; i < 4; ++i) {
    int n = ty + i * 8;
    size_t o = (size_t)(n0 + n) * 1024 + k0 + tx;
    _Float16 h, l;
    split2(tk[tx][n], &h, &l);
    thk[o] = h; tlk[o] = l;
    split2(tv[tx][n], &h, &l);
    thv[o] = h; tlv[o] = l;
  }
}

// XCD-aware bijective remap for the 1024-block fused KV gemm (1024 = 8 x 128),
// n-fast within each XCD chunk (r11 measured win on gemm_kv: 185 -> 172 us;
// r20 showed it HURTS the Q/O gemms, so it stays KV-only).
__device__ __forceinline__ void gemm_tile(int bid, int* m0, int* n0) {
  int nb = ((bid & 7) << 7) | (bid >> 3);
  *m0 = (nb >> 4) * 128;
  *n0 = (nb & 15) * 64;
}

// ---------------------------------------------------------------------------
// Pre-split MFMA GEMM (r6/r9-proven): reg-staged pure copies, tile 128x64,
// BK=32, 2-D grid (64,16), __launch_bounds__(256,4).
// MODE 0: fp32 out[m][n]. MODE 1: fp32 QKV layout.
// MODE 4: fp32 QKV layout AND split2 halves -> oh/ol (fuses xsplit2(Q)).
// ---------------------------------------------------------------------------
template <int SPLITS, int MODE>
__global__ __launch_bounds__(256, 4) void gemm_pre(const _Float16* __restrict__ Ah,
                                                   const _Float16* __restrict__ Al,
                                                   const _Float16* __restrict__ Aq,
                                                   const _Float16* __restrict__ Wth,
                                                   const _Float16* __restrict__ Wtl,
                                                   const _Float16* __restrict__ Wtq,
                                                   const float* __restrict__ bias,
                                                   float* __restrict__ outF,
                                                   _Float16* __restrict__ oh,
                                                   _Float16* __restrict__ ol) {
  extern __shared__ _Float16 sm[];
  _Float16* Xb[3];
  _Float16* Wb[3];
  for (int s = 0; s < SPLITS; ++s) {
    Xb[s] = sm + s * 4160;                 // A: 4 g-slabs x 1040
    Wb[s] = sm + SPLITS * 4160 + s * 2080; // W: 4 g-slabs x 520
  }
  const int t = threadIdx.x;
  const int m0 = blockIdx.x * 128, n0 = blockIdx.y * 64;
  const int wave = t >> 6, lane = t & 63;
  const int wm = wave & 1, wn = wave >> 1;  // wn 0..1
  const int gq = lane >> 4, ln = lane & 15;

  f4 acc[2][4];
#pragma unroll
  for (int i = 0; i < 2; ++i)
#pragma unroll
    for (int j = 0; j < 4; ++j) acc[i][j] = (f4){0.f, 0.f, 0.f, 0.f};

  for (int k0 = 0; k0 < 1024; k0 += 32) {
    __syncthreads();
#pragma unroll
    for (int i = 0; i < 2; ++i) {  // A: 512 h8 per split
      int gid = t * 2 + i;
      int m = gid >> 2, g = gid & 3;
      size_t offA = (size_t)(m0 + m) * 1024 + k0 + g * 8;
      int slot = g * 1040 + m * 8;
      *(h8*)&Xb[0][slot] = *(const h8*)(Ah + offA);
      *(h8*)&Xb[1][slot] = *(const h8*)(Al + offA);
      if (SPLITS == 3) *(h8*)&Xb[2][slot] = *(const h8*)(Aq + offA);
    }
    {  // W: 256 h8 per split
      int n = t >> 2, g = t & 3;
      size_t offW = (size_t)(n0 + n) * 1024 + k0 + g * 8;
      int slot = g * 520 + n * 8;
      *(h8*)&Wb[0][slot] = *(const h8*)(Wth + offW);
      *(h8*)&Wb[1][slot] = *(const h8*)(Wtl + offW);
      if (SPLITS == 3) *(h8*)&Wb[2][slot] = *(const h8*)(Wtq + offW);
    }
    __syncthreads();

    h8 bx[4][3];
#pragma unroll
    for (int mt = 0; mt < 4; ++mt)
#pragma unroll
      for (int s = 0; s < SPLITS; ++s)
        bx[mt][s] = *(h8*)&Xb[s][gq * 1040 + (wm * 64 + mt * 16 + ln) * 8];

#pragma unroll
    for (int nt = 0; nt < 2; ++nt) {
      h8 aw[3];
#pragma unroll
      for (int s = 0; s < SPLITS; ++s)
        aw[s] = *(h8*)&Wb[s][gq * 520 + (wn * 32 + nt * 16 + ln) * 8];
#pragma unroll
      for (int mt = 0; mt < 4; ++mt) {
        const f4 z = (f4){0.f, 0.f, 0.f, 0.f};
        f4 a = acc[nt][mt];
        a = MFMA16(aw[0], bx[mt][0], a);
        f4 t1 = MFMA16(aw[0], bx[mt][1], z);
        t1 = MFMA16(aw[1], bx[mt][0], t1);
        if (SPLITS == 3) {
          f4 t2 = MFMA16(aw[0], bx[mt][2], z);
          t2 = MFMA16(aw[1], bx[mt][1], t2);
          t2 = MFMA16(aw[2], bx[mt][0], t2);
          a += t1 * 4.8828125e-4f + t2 * 2.384185791015625e-7f;
        } else {
          a += t1 * 4.8828125e-4f;
        }
        acc[nt][mt] = a;
      }
    }
  }
#pragma unroll
  for (int nt = 0; nt < 2; ++nt)
#pragma unroll
    for (int mt = 0; mt < 4; ++mt) {
      int m = m0 + wm * 64 + mt * 16 + ln;
      int n = n0 + wn * 32 + nt * 16 + gq * 4;
      f4 r = acc[nt][mt] + *(const f4*)(bias + n);
      if (MODE == 0) {
        *(f4*)(outF + (size_t)m * 1024 + n) = r;
      } else {
        int b = m >> 12, l = m & 4095, hh = n >> 6, d = n & 63;
        size_t o = (((size_t)(b * 16 + hh)) * 4096 + l) * 64 + d;
        *(f4*)(outF + o) = r;
        if (MODE == 4) {  // also emit split2 halves (bit-identical to xsplit2)
          h4 vh, vl;
#pragma unroll
          for (int j = 0; j < 4; ++j) {
            _Float16 a2, b2;
            split2(r[j], &a2, &b2);
            vh[j] = a2; vl[j] = b2;
          }
          *(h4*)(oh + o) = vh;
          *(h4*)(ol + o) = vl;
        }
      }
    }
}

// ---------------------------------------------------------------------------
// Fused K+V projection (r10 core + r11's measured XCD swizzle win).
// ---------------------------------------------------------------------------
__global__ __launch_bounds__(256, 4) void gemm_kv(const _Float16* __restrict__ Ah,
                                                  const _Float16* __restrict__ Al,
                                                  const _Float16* __restrict__ Wthk,
                                                  const _Float16* __restrict__ Wtlk,
                                                  const _Float16* __restrict__ Wthv,
                                                  const _Float16* __restrict__ Wtlv,
                                                  const float* __restrict__ bk,
                                                  const float* __restrict__ bv,
                                                  _Float16* __restrict__ Kh,
                                                  _Float16* __restrict__ Kl,
                                                  _Float16* __restrict__ Vh,
                                                  _Float16* __restrict__ Vl) {
  __shared__ _Float16 sm[2 * 4160 + 4 * 2080];
  _Float16* Xb[2] = {sm, sm + 4160};
  _Float16* WbK[2] = {sm + 8320, sm + 8320 + 2080};
  _Float16* WbV[2] = {sm + 8320 + 4160, sm + 8320 + 4160 + 2080};
  const int t = threadIdx.x;
  int m0, n0;
  gemm_tile(blockIdx.x, &m0, &n0);
  const int wave = t >> 6, lane = t & 63;
  const int wm = wave & 1, wn = wave >> 1;
  const int gq = lane >> 4, ln = lane & 15;

  f4 accK[2][4], accV[2][4];
#pragma unroll
  for (int i = 0; i < 2; ++i)
#pragma unroll
    for (int j = 0; j < 4; ++j) {
      accK[i][j] = (f4){0.f, 0.f, 0.f, 0.f};
      accV[i][j] = (f4){0.f, 0.f, 0.f, 0.f};
    }

  for (int k0 = 0; k0 < 1024; k0 += 32) {
    __syncthreads();
#pragma unroll
    for (int i = 0; i < 2; ++i) {  // A: shared by K and V
      int gid = t * 2 + i;
      int m = gid >> 2, g = gid & 3;
      size_t offA = (size_t)(m0 + m) * 1024 + k0 + g * 8;
      int slot = g * 1040 + m * 8;
      *(h8*)&Xb[0][slot] = *(const h8*)(Ah + offA);
      *(h8*)&Xb[1][slot] = *(const h8*)(Al + offA);
    }
    {  // W: 256 h8 per array, 4 arrays
      int n = t >> 2, g = t & 3;
      size_t offW = (size_t)(n0 + n) * 1024 + k0 + g * 8;
      int slot = g * 520 + n * 8;
      *(h8*)&WbK[0][slot] = *(const h8*)(Wthk + offW);
      *(h8*)&WbK[1][slot] = *(const h8*)(Wtlk + offW);
      *(h8*)&WbV[0][slot] = *(const h8*)(Wthv + offW);
      *(h8*)&WbV[1][slot] = *(const h8*)(Wtlv + offW);
    }
    __syncthreads();

    h8 bx[4][2];
#pragma unroll
    for (int mt = 0; mt < 4; ++mt)
#pragma unroll
      for (int s = 0; s < 2; ++s)
        bx[mt][s] = *(h8*)&Xb[s][gq * 1040 + (wm * 64 + mt * 16 + ln) * 8];

#pragma unroll
    for (int nt = 0; nt < 2; ++nt) {
      int wslot = gq * 520 + (wn * 32 + nt * 16 + ln) * 8;
      h8 awk0 = *(h8*)&WbK[0][wslot];
      h8 awk1 = *(h8*)&WbK[1][wslot];
      h8 awv0 = *(h8*)&WbV[0][wslot];
      h8 awv1 = *(h8*)&WbV[1][wslot];
#pragma unroll
      for (int mt = 0; mt < 4; ++mt) {
        const f4 z = (f4){0.f, 0.f, 0.f, 0.f};
        f4 a = accK[nt][mt];
        a = MFMA16(awk0, bx[mt][0], a);
        f4 t1 = MFMA16(awk0, bx[mt][1], z);
        t1 = MFMA16(awk1, bx[mt][0], t1);
        accK[nt][mt] = a + t1 * 4.8828125e-4f;

        f4 b = accV[nt][mt];
        b = MFMA16(awv0, bx[mt][0], b);
        f4 t2 = MFMA16(awv0, bx[mt][1], z);
        t2 = MFMA16(awv1, bx[mt][0], t2);
        accV[nt][mt] = b + t2 * 4.8828125e-4f;
      }
    }
  }
#pragma unroll
  for (int nt = 0; nt < 2; ++nt)
#pragma unroll
    for (int mt = 0; mt < 4; ++mt) {
      int m = m0 + wm * 64 + mt * 16 + ln;
      int n = n0 + wn * 32 + nt * 16 + gq * 4;
      int b = m >> 12, l = m & 4095, hh = n >> 6, d = n & 63;
      size_t o = (((size_t)(b * 16 + hh)) * 4096 + l) * 64 + d;
      f4 rk = accK[nt][mt] + *(const f4*)(bk + n);
      f4 rv = accV[nt][mt] + *(const f4*)(bv + n);
      h4 kh, kl, vh, vl;
#pragma unroll
      for (int j = 0; j < 4; ++j) {
        _Float16 p, q;
        split2(rk[j], &p, &q); kh[j] = p; kl[j] = q;
        split2(rv[j], &p, &q); vh[j] = p; vl[j] = q;
      }
      *(h4*)(Kh + o) = kh;
      *(h4*)(Kl + o) = kl;
      *(h4*)(Vh + o) = vh;
      *(h4*)(Vl + o) = vl;
    }
}

// ---------------------------------------------------------------------------
// init: cent0 = Q[:,:, :256, :] stored as split3; fused cnorm.
// (Cqg kept for update's empty-cluster reconstruction fidelity.)
// ---------------------------------------------------------------------------
__global__ __launch_bounds__(256) void init_cent_fused(const float* __restrict__ Q,
                                                       float* __restrict__ cnorm,
                                                       _Float16* __restrict__ Chg,
                                                       _Float16* __restrict__ Clg,
                                                       _Float16* __restrict__ Cqg) {
  const int gid = blockIdx.x * 4 + (threadIdx.x >> 6);  // bh*256+c
  const int bh = gid >> 8, c = gid & 255;
  const int lane = threadIdx.x & 63;
  float v = Q[((size_t)bh * 4096 + c) * 64 + lane];
  size_t ci = (size_t)gid * 64 + lane;
  _Float16 a, b, q;
  split3(v, &a, &b, &q);
  Chg[ci] = a; Clg[ci] = b; Cqg[ci] = q;
  float ss = v * v;
#pragma unroll
  for (int off = 1; off < 64; off <<= 1) ss += __shfl_xor(ss, off, 64);
  if (lane == 0) cnorm[gid] = ss;
}

// ---------------------------------------------------------------------------
// MFMA assign, 3-term distances, rt=4, grid 512 — NO LDS: centroid B-frags
// and cnorm are loaded directly from global (L2-resident, 512 KB total) into
// VGPRs. Deletes both barriers and the staged-copy rounds; occupancy no
// longer LDS-capped. Values bit-identical to the r17/r21 staged version
// (same data, same MFMA order, same strict-< ascending-c tie-break).
// ---------------------------------------------------------------------------
__global__ __launch_bounds__(256) void assign_mfma(const _Float16* __restrict__ Qh,
                                                   const _Float16* __restrict__ Ql,
                                                   const _Float16* __restrict__ Chg,
                                                   const _Float16* __restrict__ Clg,
                                                   const float* __restrict__ cnorm,
                                                   int* __restrict__ assign,
                                                   unsigned* __restrict__ mask) {
  const int t = threadIdx.x;
  const int wave = t >> 6, lane = t & 63;
  const int bh = blockIdx.x & 31, lch = blockIdx.x >> 5;  // lch 0..15
  const int l0 = lch * 256;
  const int gq = lane >> 4, ln = lane & 15;

  // A-frags: this wave's 64 Q rows (pure loads)
  h8 ah[4][2], al[4][2];
#pragma unroll
  for (int rt = 0; rt < 4; ++rt)
#pragma unroll
    for (int ks = 0; ks < 2; ++ks) {
      size_t off =
          ((size_t)bh * 4096 + l0 + wave * 64 + rt * 16 + ln) * 64 + ks * 32 + gq * 8;
      ah[rt][ks] = *(const h8*)(Qh + off);
      al[rt][ks] = *(const h8*)(Ql + off);
    }

  float bestv[4][4];
  int bestc[4][4];
#pragma unroll
  for (int rt = 0; rt < 4; ++rt)
#pragma unroll
    for (int j = 0; j < 4; ++j) { bestv[rt][j] = 3.4e38f; bestc[rt][j] = 0; }

  // 16 c-tiles of 16 clusters, ascending (preserves first-index tie-break).
#pragma unroll
  for (int ct = 0; ct < 16; ++ct) {
    const f4 z = (f4){0.f, 0.f, 0.f, 0.f};
    f4 a0[4] = {z, z, z, z}, a1[4] = {z, z, z, z};
#pragma unroll
    for (int ks = 0; ks < 2; ++ks) {
      // B-frag for this (ct,ks): centroid row c = ct*16+ln, k-slice ks
      size_t coff = ((size_t)(bh * 256 + ct * 16 + ln)) * 64 + ks * 32 + gq * 8;
      h8 bh_ = *(const h8*)(Chg + coff);
      h8 bl_ = *(const h8*)(Clg + coff);
#pragma unroll
      for (int rt = 0; rt < 4; ++rt) {
        a0[rt] = MFMA16(ah[rt][ks], bh_, a0[rt]);
        a1[rt] = MFMA16(ah[rt][ks], bl_, a1[rt]);
        a1[rt] = MFMA16(al[rt][ks], bh_, a1[rt]);
      }
    }
    float cnv = cnorm[bh * 256 + ct * 16 + ln];
    int cbase = ct * 16 + ln;
#pragma unroll
    for (int rt = 0; rt < 4; ++rt) {
      f4 dot = a0[rt] + a1[rt] * 4.8828125e-4f;
#pragma unroll
      for (int j = 0; j < 4; ++j) {
        float dist = fmaf(-2.f, dot[j], cnv);
        if (dist < bestv[rt][j]) { bestv[rt][j] = dist; bestc[rt][j] = cbase; }
      }
    }
  }
#pragma unroll
  for (int rt = 0; rt < 4; ++rt)
#pragma unroll
    for (int j = 0; j < 4; ++j) {
      float v = bestv[rt][j];
      int c = bestc[rt][j];
#pragma unroll
      for (int off = 1; off < 16; off <<= 1) {
        float ov = __shfl_xor(v, off, 64);
        int oc = __shfl_xor(c, off, 64);
        if (ov < v || (ov == v && oc < c)) { v = ov; c = oc; }
      }
      if (ln == 0) {
        int l = l0 + wave * 64 + rt * 16 + gq * 4 + j;
        assign[(size_t)bh * 4096 + l] = c;
        atomicOr(&mask[(((size_t)bh * 256 + c) << 7) + (l >> 5)], 1u << (l & 31));
      }
    }
}

// ---------------------------------------------------------------------------
// centroid update, 4-way wave-parallel scan (r18-proven). Clears mask;
// fused cnorm + split3. Reads fp32 Q.
// ---------------------------------------------------------------------------
__global__ __launch_bounds__(256) void update4_kernel(const float* __restrict__ Q,
                                                      unsigned* __restrict__ mask,
                                                      float* __restrict__ cnorm,
                                                      _Float16* __restrict__ Chg,
                                                      _Float16* __restrict__ Clg,
                                                      _Float16* __restrict__ Cqg) {
  const int gid = blockIdx.x;           // bh*256+c
  const int bh = gid >> 8;
  const int t = threadIdx.x;
  const int wave = t >> 6, lane = t & 63;
  __shared__ unsigned w[128];
  __shared__ float psum[4][64];
  __shared__ int pcnt[4];
  unsigned* mp = mask + ((size_t)gid << 7);
  if (t < 128) {
    w[t] = mp[t];
    mp[t] = 0u;  // self-restoring for next iteration / next call
  }
  __syncthreads();
  float sum = 0.f;
  int cnt = 0;
  const float* qb = Q + (size_t)bh * 4096 * 64 + lane;
  const int i0 = wave * 32;
  for (int i = i0; i < i0 + 32; ++i) {
    unsigned u = w[i];
    while (u) {  // wave-uniform
      int b = __ffs(u) - 1;
      u &= u - 1;
      int l = i * 32 + b;
      sum += qb[(size_t)l * 64];
      ++cnt;
    }
  }
  psum[wave][lane] = sum;
  if (lane == 0) pcnt[wave] = cnt;
  __syncthreads();
  if (wave == 0) {
    int total = (pcnt[0] + pcnt[1]) + (pcnt[2] + pcnt[3]);
    size_t ci = (size_t)gid * 64 + lane;
    float v;
    if (total) {
      float s = (psum[0][lane] + psum[1][lane]) + (psum[2][lane] + psum[3][lane]);
      v = s / (float)total;
    } else {
      v = (float)Chg[ci] + (float)Clg[ci] * 4.8828125e-4f +
          (float)Cqg[ci] * 2.384185791015625e-7f;
    }
    _Float16 a, b2, q;
    split3(v, &a, &b2, &q);
    Chg[ci] = a; Clg[ci] = b2; Cqg[ci] = q;
    float ss = v * v;
#pragma unroll
    for (int off = 1; off < 64; off <<= 1) ss += __shfl_xor(ss, off, 64);
    if (lane == 0) cnorm[gid] = ss;
  }
}

// ---------------------------------------------------------------------------
// MFMA flash attention. 16 uniform chunks of 4x64 l-tiles; grid 512.
// ---------------------------------------------------------------------------
#define NCH 16
__global__ __launch_bounds__(256) void attn_mfma(const _Float16* __restrict__ Kh,
                                                 const _Float16* __restrict__ Kl,
                                                 const _Float16* __restrict__ Vh,
                                                 const _Float16* __restrict__ Vl,
                                                 const _Float16* __restrict__ Chg,
                                                 const _Float16* __restrict__ Clg,
                                                 float* __restrict__ pacc,
                                                 float* __restrict__ pml) {
  __shared__ _Float16 KhS[4160], KlS[4160];    // 8 slabs x 520
  __shared__ _Float16 VhT[64 * 72], VlT[64 * 72];
  __shared__ _Float16 Ph[4][16 * 72], Pl[4][16 * 72];
  const int bh = blockIdx.x & 31, ch = blockIdx.x >> 5;  // ch 0..15
  const int t = threadIdx.x;
  const int wave = t >> 6, lane = t & 63, gq = lane >> 4, ln = lane & 15;

  h8 cah[4][2], cal[4][2];
#pragma unroll
  for (int cb = 0; cb < 4; ++cb)
#pragma unroll
    for (int ks = 0; ks < 2; ++ks) {
      size_t off = ((size_t)bh * 256 + wave * 64 + cb * 16 + ln) * 64 + ks * 32 + gq * 8;
      cah[cb][ks] = *(const h8*)(Chg + off);
      cal[cb][ks] = *(const h8*)(Clg + off);
    }

  f4 mr[4], ls[4], acc[4][4];
#pragma unroll
  for (int cb = 0; cb < 4; ++cb) {
    mr[cb] = (f4){-3.0e38f, -3.0e38f, -3.0e38f, -3.0e38f};
    ls[cb] = (f4){0.f, 0.f, 0.f, 0.f};
#pragma unroll
    for (int dt = 0; dt < 4; ++dt) acc[cb][dt] = (f4){0.f, 0.f, 0.f, 0.f};
  }

  for (int lt = 0; lt < 4; ++lt) {
    const int l0 = (ch * 4 + lt) * 64;
    __syncthreads();
#pragma unroll
    for (int i = 0; i < 2; ++i) {  // stage K (h8 copies) + V (transposed)
      int gid = t * 2 + i;
      int l = gid >> 3, g = gid & 7;
      size_t src = ((size_t)bh * 4096 + l0 + l) * 64 + g * 8;
      int dst = g * 520 + l * 8;
      *(h8*)&KhS[dst] = *(const h8*)(Kh + src);
      *(h8*)&KlS[dst] = *(const h8*)(Kl + src);
      h8 vh = *(const h8*)(Vh + src);
      h8 vl = *(const h8*)(Vl + src);
#pragma unroll
      for (int j = 0; j < 8; ++j) {
        VhT[(g * 8 + j) * 72 + l] = vh[j];
        VlT[(g * 8 + j) * 72 + l] = vl[j];
      }
    }
    __syncthreads();

#pragma unroll
    for (int cb = 0; cb < 4; ++cb) {
      // ---- QK^T: S rows c (=gq*4+j), cols l (=st*16+ln)
      f4 s[4];
#pragma unroll
      for (int st = 0; st < 4; ++st) {
        const f4 z = (f4){0.f, 0.f, 0.f, 0.f};
        f4 a0 = z, a1 = z;
#pragma unroll
        for (int ks = 0; ks < 2; ++ks) {
          int bslot = (ks * 4 + gq) * 520 + (st * 16 + ln) * 8;
          h8 kbh = *(h8*)&KhS[bslot];
          h8 kbl = *(h8*)&KlS[bslot];
          a0 = MFMA16(cah[cb][ks], kbh, a0);
          a1 = MFMA16(cah[cb][ks], kbl, a1);
          a1 = MFMA16(cal[cb][ks], kbh, a1);
        }
        s[st] = (a0 + a1 * 4.8828125e-4f) * 0.125f;
      }
      // ---- online softmax (per c = gq*4+j)
      f4 ml;
#pragma unroll
      for (int j = 0; j < 4; ++j)
        ml[j] = fmaxf(fmaxf(s[0][j], s[1][j]), fmaxf(s[2][j], s[3][j]));
#pragma unroll
      for (int off = 1; off < 16; off <<= 1)
#pragma unroll
        for (int j = 0; j < 4; ++j) ml[j] = fmaxf(ml[j], __shfl_xor(ml[j], off, 64));
      f4 mn, corr;
#pragma unroll
      for (int j = 0; j < 4; ++j) {
        mn[j] = fmaxf(mr[cb][j], ml[j]);
        corr[j] = __expf(mr[cb][j] - mn[j]);
      }
      f4 psum = (f4){0.f, 0.f, 0.f, 0.f};
#pragma unroll
      for (int st = 0; st < 4; ++st) {
#pragma unroll
        for (int j = 0; j < 4; ++j) {
          float p = __expf(s[st][j] - mn[j]);
          psum[j] += p;
          _Float16 a, b;
          split2(p, &a, &b);
          Ph[wave][(gq * 4 + j) * 72 + st * 16 + ln] = a;
          Pl[wave][(gq * 4 + j) * 72 + st * 16 + ln] = b;
        }
      }
#pragma unroll
      for (int off = 1; off < 16; off <<= 1)
#pragma unroll
        for (int j = 0; j < 4; ++j) psum[j] += __shfl_xor(psum[j], off, 64);
      ls[cb] = ls[cb] * corr + psum;
      mr[cb] = mn;
#pragma unroll
      for (int dt = 0; dt < 4; ++dt) acc[cb][dt] *= corr;
      // ---- PV (same-wave LDS handoff)
#pragma unroll
      for (int ks = 0; ks < 2; ++ks) {
        h8 pah = *(h8*)&Ph[wave][ln * 72 + ks * 32 + gq * 8];
        h8 pal = *(h8*)&Pl[wave][ln * 72 + ks * 32 + gq * 8];
#pragma unroll
        for (int dt = 0; dt < 4; ++dt) {
          int vslot = (dt * 16 + ln) * 72 + ks * 32 + gq * 8;
          h8 vbh = *(h8*)&VhT[vslot];
          h8 vbl = *(h8*)&VlT[vslot];
          acc[cb][dt] = MFMA16(pah, vbh, acc[cb][dt]);
          const f4 z = (f4){0.f, 0.f, 0.f, 0.f};
          f4 t1 = MFMA16(pah, vbl, z);
          t1 = MFMA16(pal, vbh, t1);
          acc[cb][dt] += t1 * 4.8828125e-4f;
        }
      }
    }
  }
  // ---- write partials
#pragma unroll
  for (int cb = 0; cb < 4; ++cb) {
    int crow = wave * 64 + cb * 16 + gq * 4;
#pragma unroll
    for (int dt = 0; dt < 4; ++dt)
#pragma unroll
      for (int j = 0; j < 4; ++j)
        pacc[((size_t)ch * 8192 + bh * 256 + crow + j) * 64 + dt * 16 + ln] = acc[cb][dt][j];
    if (ln == 0) {
#pragma unroll
      for (int j = 0; j < 4; ++j) {
        size_t r = (size_t)ch * 8192 + bh * 256 + crow + j;
        pml[r * 2 + 0] = mr[cb][j];
        pml[r * 2 + 1] = ls[cb][j];
      }
    }
  }
}

// ---------------------------------------------------------------------------
// merge 16 chunk-partials -> Oc[bh*256+c][64]
// ---------------------------------------------------------------------------
__global__ __launch_bounds__(256) void merge_kernel(const float* __restrict__ pacc,
                                                    const float* __restrict__ pml,
                                                    float* __restrict__ Oc) {
  const int row = blockIdx.x * 4 + (threadIdx.x >> 6);
  const int lane = threadIdx.x & 63;
  float M = -3.0e38f;
#pragma unroll
  for (int q = 0; q < NCH; ++q) M = fmaxf(M, pml[((size_t)q * 8192 + row) * 2]);
  float S = 0.f, o = 0.f;
#pragma unroll
  for (int q = 0; q < NCH; ++q) {
    size_t r = (size_t)q * 8192 + row;
    float w = __expf(pml[r * 2] - M);
    S = fmaf(w, pml[r * 2 + 1], S);
    o = fmaf(w, pacc[r * 64 + lane], o);
  }
  Oc[(size_t)row * 64 + lane] = o / S;
}

// ---------------------------------------------------------------------------
// gather + split2: Oh/Ol[b][l][h*64+d] = split2(Oc[b][h][assign[b][h][l]][d])
// ---------------------------------------------------------------------------
__global__ void gather_kernel(const float* __restrict__ Oc,
                              const int* __restrict__ assign,
                              _Float16* __restrict__ Oh,
                              _Float16* __restrict__ Ol) {
  size_t idx = (size_t)blockIdx.x * 256 + threadIdx.x;
  int d4 = (int)(idx & 15) * 4;
  size_t rest = idx >> 4;
  int h = (int)(rest & 15);
  size_t bl = rest >> 4;
  int b = (int)(bl >> 12);
  int l = (int)(bl & 4095);
  int bh = b * 16 + h;
  int a = assign[(size_t)bh * 4096 + l];
  float4 v = *(const float4*)(Oc + (((size_t)bh * 256 + a) * 64 + d4));
  float xs[4] = {v.x, v.y, v.z, v.w};
  h4 vh, vl;
#pragma unroll
  for (int j = 0; j < 4; ++j) {
    _Float16 p, q;
    split2(xs[j], &p, &q);
    vh[j] = p; vl[j] = q;
  }
  size_t o = bl * 1024 + (size_t)h * 64 + d4;
  *(h4*)(Oh + o) = vh;
  *(h4*)(Ol + o) = vl;
}

// ---------------------------------------------------------------------------
extern "C" void kernel_launch(void* const* d_in, const int* in_sizes, int n_in,
                              void* d_out, int out_size, void* d_ws, size_t ws_size,
                              hipStream_t stream) {
  const float* X  = (const float*)d_in[0];
  const float* Wq = (const float*)d_in[3];
  const float* bq = (const float*)d_in[4];
  const float* Wk = (const float*)d_in[5];
  const float* bk = (const float*)d_in[6];
  const float* Wv = (const float*)d_in[7];
  const float* bv = (const float*)d_in[8];
  const float* Wo = (const float*)d_in[9];
  const float* bo = (const float*)d_in[10];
  float* out = (float*)d_out;

  // ---- Workspace (floats), total 26,353,664 == proven budget (r19 layout).
  // R1 [0, 8,388,608):  A-B: Q fp32 | C: Wthk/Wtlk/Wthv/Wtlv | D: pacc
  // R2 [8,388,608, 16,777,216): A: WthQ/WtlQ@0 + Qh@+1,048,576 (A-B) |
  //                             C-D: Kh/Kl | E: Oh/Ol
  // R3 [16,777,216, 25,165,824): A-B: Ql@0 | B: mask@+4,194,304 | C-D: Vh/Vl |
  //                              D-E: Oc@0 | E: Wth3/Wtl3@+524,288
  // R4 [25,165,824, 26,353,664): cnorm | assign | Chg | Clg | Cqg | pml
  // d_out (8,388,608 fl = 16,777,216 halfs): A-C: Xh/Xl | E: final output.
  float* W0 = (float*)d_ws;
  float* R1 = W0;
  float* R2 = W0 + 8388608;
  float* R3 = W0 + 16777216;
  float* R4 = W0 + 25165824;

  _Float16* Xh = (_Float16*)out;                  // 8,388,608 halfs
  _Float16* Xl = (_Float16*)out + 8388608;        // 8,388,608 halfs

  float* Q = R1;
  _Float16* WthQ = (_Float16*)R2;
  _Float16* WtlQ = (_Float16*)(R2 + 524288);
  _Float16* Qh = (_Float16*)(R2 + 1048576);       // A-B (written by MODE-4 gemm)
  _Float16* Ql = (_Float16*)R3;                   // A-B

  float* cnorm = R4;                              // 8,192
  int* assign  = (int*)(R4 + 8192);               // 131,072
  _Float16* Chg = (_Float16*)(R4 + 139264);       // 524,288 halfs
  _Float16* Clg = (_Float16*)(R4 + 401408);
  _Float16* Cqg = (_Float16*)(R4 + 663552);
  float* pml    = R4 + 925696;                    // 16*8192*2 = 262,144
  unsigned* mask = (unsigned*)(R3 + 4194304);     // 1,048,576 words (phase B)

  _Float16* Wthk = (_Float16*)R1;                 // phase C (Q dead)
  _Float16* Wtlk = (_Float16*)(R1 + 524288);
  _Float16* Wthv = (_Float16*)(R1 + 1048576);
  _Float16* Wtlv = (_Float16*)(R1 + 1572864);
  _Float16* Kh = (_Float16*)R2;                   // C -> D (WthQ/Qh dead)
  _Float16* Kl = (_Float16*)(R2 + 4194304);
  _Float16* Vh = (_Float16*)R3;                   // C -> D (Ql, mask dead)
  _Float16* Vl = (_Float16*)(R3 + 4194304);

  float* pacc = R1;                               // D
  float* Oc   = R3;                               // D -> E (Vh dead)

  _Float16* Oh = (_Float16*)R2;                   // E (Kh/Kl dead)
  _Float16* Ol = (_Float16*)(R2 + 4194304);
  _Float16* Wth3 = (_Float16*)(R3 + 524288);      // E (after Oc)
  _Float16* Wtl3 = (_Float16*)(R3 + 1048576);

  dim3 tgrid(32, 32);
  dim3 ggrid(64, 16);                              // 128x64 tiles -> 1024 blocks
  size_t smem2 = (size_t)(2 * 4160 + 2 * 2080) * sizeof(_Float16);  // 24,960 B

  // Phase A: pre-split X (2-way); Q projection (SPLITS=2, MODE 4: also emits
  // Qh/Ql split2 halves in the epilogue -> xsplit2(Q) pass eliminated).
  xsplit2_kernel<<<8192, 256, 0, stream>>>(X, Xh, Xl);
  tsplit_kernel<<<tgrid, 256, 0, stream>>>(Wq, WthQ, WtlQ, nullptr);
  gemm_pre<2, 4><<<ggrid, 256, smem2, stream>>>(Xh, Xl, nullptr, WthQ, WtlQ, nullptr,
                                                bq, Q, Qh, Ql);

  // Phase B: k-means (11 assign/update rounds); assign LDS-free; update 4-wave
  init_cent_fused<<<2048, 256, 0, stream>>>(Q, cnorm, Chg, Clg, Cqg);
  hipMemsetAsync(mask, 0, 1048576 * sizeof(unsigned), stream);
  for (int it = 0; it < 11; ++it) {
    assign_mfma<<<512, 256, 0, stream>>>(Qh, Ql, Chg, Clg, cnorm, assign, mask);
    update4_kernel<<<8192, 256, 0, stream>>>(Q, mask, cnorm, Chg, Clg, Cqg);
  }

  // Phase C: fused K+V projection (XCD-swizzled); single fused W-transpose.
  tsplit_kv_kernel<<<tgrid, 256, 0, stream>>>(Wk, Wv, Wthk, Wtlk, Wthv, Wtlv);
  gemm_kv<<<1024, 256, 0, stream>>>(Xh, Xl, Wthk, Wtlk, Wthv, Wtlv, bk, bv,
                                    Kh, Kl, Vh, Vl);

  // Phase D: clustered attention (16 uniform L-chunks) + merge
  attn_mfma<<<512, 256, 0, stream>>>(Kh, Kl, Vh, Vl, Chg, Clg, pacc, pml);
  merge_kernel<<<2048, 256, 0, stream>>>(pacc, pml, Oc);

  // Phase E: gather (emits split2) + output projection
  gather_kernel<<<8192, 256, 0, stream>>>(Oc, assign, Oh, Ol);
  tsplit_kernel<<<tgrid, 256, 0, stream>>>(Wo, Wth3, Wtl3, nullptr);
  gemm_pre<2, 0><<<ggrid, 256, smem2, stream>>>(Oh, Ol, nullptr, Wth3, Wtl3, nullptr, bo,
                                                out, nullptr, nullptr);
}

// Round 23
// 1132.977 us; speedup vs baseline: 1.3076x; 1.3076x over previous
//
#include <hip/hip_runtime.h>
#include <cstddef>

// B=2, L=4096, HID=1024, H=16, D=64, C=256, KM_ITERS=10 (11 assign/update rounds)
// BH=32, M=B*L=8192

typedef _Float16 h8 __attribute__((ext_vector_type(8)));
typedef _Float16 h4 __attribute__((ext_vector_type(4)));
typedef float f4 __attribute__((ext_vector_type(4)));

#define MFMA16(a, b, c) __builtin_amdgcn_mfma_f32_16x16x32_f16((a), (b), (c), 0, 0, 0)

// fp32 -> f16 splits. lo scaled by 2^11, quad term by 2^22 (avoids f16 subnormals).
__device__ __forceinline__ void split3(float x, _Float16* h, _Float16* l, _Float16* q) {
  _Float16 hh = (_Float16)x;
  float r1 = x - (float)hh;
  _Float16 ll = (_Float16)(r1 * 2048.0f);
  float r2 = fmaf((float)ll, -4.8828125e-4f, r1);
  *h = hh; *l = ll; *q = (_Float16)(r2 * 4194304.0f);
}
__device__ __forceinline__ void split2(float x, _Float16* h, _Float16* l) {
  _Float16 hh = (_Float16)x;
  float r1 = x - (float)hh;
  *h = hh; *l = (_Float16)(r1 * 2048.0f);
}

// ---------------------------------------------------------------------------
// elementwise split2 of an 8,388,608-float array (X only now).
// ---------------------------------------------------------------------------
__global__ __launch_bounds__(256) void xsplit2_kernel(const float* __restrict__ X,
                                                      _Float16* __restrict__ xh,
                                                      _Float16* __restrict__ xl) {
  size_t i = ((size_t)blockIdx.x * 256 + threadIdx.x) * 4;
  float4 v = *(const float4*)(X + i);
  float xs[4] = {v.x, v.y, v.z, v.w};
  h4 vh, vl;
#pragma unroll
  for (int j = 0; j < 4; ++j) {
    _Float16 a, b;
    split2(xs[j], &a, &b);
    vh[j] = a; vl[j] = b;
  }
  *(h4*)(xh + i) = vh;
  *(h4*)(xl + i) = vl;
}

// ---------------------------------------------------------------------------
// W[1024][1024] -> Wt_h/l/q[n][k] (transposed + split). tq may be null.
// ---------------------------------------------------------------------------
__global__ __launch_bounds__(256) void tsplit_kernel(const float* __restrict__ W,
                                                     _Float16* __restrict__ th,
                                                     _Float16* __restrict__ tl,
                                                     _Float16* __restrict__ tq) {
  __shared__ float tile[32][33];
  const int n0 = blockIdx.x * 32, k0 = blockIdx.y * 32;
  const int tx = threadIdx.x & 31, ty = threadIdx.x >> 5;
#pragma unroll
  for (int i = 0; i < 4; ++i) {
    int k = ty + i * 8;
    tile[k][tx] = W[(size_t)(k0 + k) * 1024 + n0 + tx];
  }
  __syncthreads();
#pragma unroll
  for (int i = 0; i < 4; ++i) {
    int n = ty + i * 8;
    float x = tile[tx][n];
    _Float16 h, l, q;
    split3(x, &h, &l, &q);
    size_t o = (size_t)(n0 + n) * 1024 + k0 + tx;
    th[o] = h; tl[o] = l;
    if (tq) tq[o] = q;
  }
}

// ---------------------------------------------------------------------------
// Fused transpose+split of BOTH Wk and Wv in one launch (r19-proven).
// ---------------------------------------------------------------------------
__global__ __launch_bounds__(256) void tsplit_kv_kernel(const float* __restrict__ Wk,
                                                        const float* __restrict__ Wv,
                                                        _Float16* __restrict__ thk,
                                                        _Float16* __restrict__ tlk,
                                                        _Float16* __restrict__ thv,
                                                        _Float16* __restrict__ tlv) {
  __shared__ float tk[32][33];
  __shared__ float tv[32][33];
  const int n0 = blockIdx.x * 32, k0 = blockIdx.y * 32;
  const int tx = threadIdx.x & 31, ty = threadIdx.x >> 5;
#pragma unroll
  for (int i = 0; i < 4; ++i) {
    int k = ty + i * 8;
    tk[k][tx] = Wk[(size_t)(k0 + k) * 1024 + n0 + tx];
    tv[k][tx] = Wv[(size_t)(k0 + k) * 1024 + n0 + tx];
  }
  __syncthreads();
#pragma unroll
  for (int i = 0; i < 4; ++i) {
    int n = ty + i * 8;
    size_t o = (size_t)(n0 + n) * 1024 + k0 + tx;
    _Float16 h, l;
    split2(tk[tx][n], &h, &l);
    thk[o] = h; tlk[o] = l;
    split2(tv[tx][n], &h, &l);
    thv[o] = h; tlv[o] = l;
  }
}

// XCD-aware bijective remap for the 1024-block fused KV gemm (1024 = 8 x 128),
// n-fast within each XCD chunk (r11 measured win on gemm_kv: 185 -> 172 us;
// r20 showed it HURTS the Q/O gemms, so it stays KV-only).
__device__ __forceinline__ void gemm_tile(int bid, int* m0, int* n0) {
  int nb = ((bid & 7) << 7) | (bid >> 3);
  *m0 = (nb >> 4) * 128;
  *n0 = (nb & 15) * 64;
}

// ---------------------------------------------------------------------------
// Pre-split MFMA GEMM (r6/r9-proven): reg-staged pure copies, tile 128x64,
// BK=32, 2-D grid (64,16), __launch_bounds__(256,4).
// MODE 0: fp32 out[m][n]. MODE 1: fp32 QKV layout.
// MODE 4: fp32 QKV layout AND split2 halves -> oh/ol (fuses xsplit2(Q)).
// ---------------------------------------------------------------------------
template <int SPLITS, int MODE>
__global__ __launch_bounds__(256, 4) void gemm_pre(const _Float16* __restrict__ Ah,
                                                   const _Float16* __restrict__ Al,
                                                   const _Float16* __restrict__ Aq,
                                                   const _Float16* __restrict__ Wth,
                                                   const _Float16* __restrict__ Wtl,
                                                   const _Float16* __restrict__ Wtq,
                                                   const float* __restrict__ bias,
                                                   float* __restrict__ outF,
                                                   _Float16* __restrict__ oh,
                                                   _Float16* __restrict__ ol) {
  extern __shared__ _Float16 sm[];
  _Float16* Xb[3];
  _Float16* Wb[3];
  for (int s = 0; s < SPLITS; ++s) {
    Xb[s] = sm + s * 4160;                 // A: 4 g-slabs x 1040
    Wb[s] = sm + SPLITS * 4160 + s * 2080; // W: 4 g-slabs x 520
  }
  const int t = threadIdx.x;
  const int m0 = blockIdx.x * 128, n0 = blockIdx.y * 64;
  const int wave = t >> 6, lane = t & 63;
  const int wm = wave & 1, wn = wave >> 1;  // wn 0..1
  const int gq = lane >> 4, ln = lane & 15;

  f4 acc[2][4];
#pragma unroll
  for (int i = 0; i < 2; ++i)
#pragma unroll
    for (int j = 0; j < 4; ++j) acc[i][j] = (f4){0.f, 0.f, 0.f, 0.f};

  for (int k0 = 0; k0 < 1024; k0 += 32) {
    __syncthreads();
#pragma unroll
    for (int i = 0; i < 2; ++i) {  // A: 512 h8 per split
      int gid = t * 2 + i;
      int m = gid >> 2, g = gid & 3;
      size_t offA = (size_t)(m0 + m) * 1024 + k0 + g * 8;
      int slot = g * 1040 + m * 8;
      *(h8*)&Xb[0][slot] = *(const h8*)(Ah + offA);
      *(h8*)&Xb[1][slot] = *(const h8*)(Al + offA);
      if (SPLITS == 3) *(h8*)&Xb[2][slot] = *(const h8*)(Aq + offA);
    }
    {  // W: 256 h8 per split
      int n = t >> 2, g = t & 3;
      size_t offW = (size_t)(n0 + n) * 1024 + k0 + g * 8;
      int slot = g * 520 + n * 8;
      *(h8*)&Wb[0][slot] = *(const h8*)(Wth + offW);
      *(h8*)&Wb[1][slot] = *(const h8*)(Wtl + offW);
      if (SPLITS == 3) *(h8*)&Wb[2][slot] = *(const h8*)(Wtq + offW);
    }
    __syncthreads();

    h8 bx[4][3];
#pragma unroll
    for (int mt = 0; mt < 4; ++mt)
#pragma unroll
      for (int s = 0; s < SPLITS; ++s)
        bx[mt][s] = *(h8*)&Xb[s][gq * 1040 + (wm * 64 + mt * 16 + ln) * 8];

#pragma unroll
    for (int nt = 0; nt < 2; ++nt) {
      h8 aw[3];
#pragma unroll
      for (int s = 0; s < SPLITS; ++s)
        aw[s] = *(h8*)&Wb[s][gq * 520 + (wn * 32 + nt * 16 + ln) * 8];
#pragma unroll
      for (int mt = 0; mt < 4; ++mt) {
        const f4 z = (f4){0.f, 0.f, 0.f, 0.f};
        f4 a = acc[nt][mt];
        a = MFMA16(aw[0], bx[mt][0], a);
        f4 t1 = MFMA16(aw[0], bx[mt][1], z);
        t1 = MFMA16(aw[1], bx[mt][0], t1);
        if (SPLITS == 3) {
          f4 t2 = MFMA16(aw[0], bx[mt][2], z);
          t2 = MFMA16(aw[1], bx[mt][1], t2);
          t2 = MFMA16(aw[2], bx[mt][0], t2);
          a += t1 * 4.8828125e-4f + t2 * 2.384185791015625e-7f;
        } else {
          a += t1 * 4.8828125e-4f;
        }
        acc[nt][mt] = a;
      }
    }
  }
#pragma unroll
  for (int nt = 0; nt < 2; ++nt)
#pragma unroll
    for (int mt = 0; mt < 4; ++mt) {
      int m = m0 + wm * 64 + mt * 16 + ln;
      int n = n0 + wn * 32 + nt * 16 + gq * 4;
      f4 r = acc[nt][mt] + *(const f4*)(bias + n);
      if (MODE == 0) {
        *(f4*)(outF + (size_t)m * 1024 + n) = r;
      } else {
        int b = m >> 12, l = m & 4095, hh = n >> 6, d = n & 63;
        size_t o = (((size_t)(b * 16 + hh)) * 4096 + l) * 64 + d;
        *(f4*)(outF + o) = r;
        if (MODE == 4) {  // also emit split2 halves (bit-identical to xsplit2)
          h4 vh, vl;
#pragma unroll
          for (int j = 0; j < 4; ++j) {
            _Float16 a2, b2;
            split2(r[j], &a2, &b2);
            vh[j] = a2; vl[j] = b2;
          }
          *(h4*)(oh + o) = vh;
          *(h4*)(ol + o) = vl;
        }
      }
    }
}

// ---------------------------------------------------------------------------
// Fused K+V projection (r10 core + r11's measured XCD swizzle win).
// ---------------------------------------------------------------------------
__global__ __launch_bounds__(256, 4) void gemm_kv(const _Float16* __restrict__ Ah,
                                                  const _Float16* __restrict__ Al,
                                                  const _Float16* __restrict__ Wthk,
                                                  const _Float16* __restrict__ Wtlk,
                                                  const _Float16* __restrict__ Wthv,
                                                  const _Float16* __restrict__ Wtlv,
                                                  const float* __restrict__ bk,
                                                  const float* __restrict__ bv,
                                                  _Float16* __restrict__ Kh,
                                                  _Float16* __restrict__ Kl,
                                                  _Float16* __restrict__ Vh,
                                                  _Float16* __restrict__ Vl) {
  __shared__ _Float16 sm[2 * 4160 + 4 * 2080];
  _Float16* Xb[2] = {sm, sm + 4160};
  _Float16* WbK[2] = {sm + 8320, sm + 8320 + 2080};
  _Float16* WbV[2] = {sm + 8320 + 4160, sm + 8320 + 4160 + 2080};
  const int t = threadIdx.x;
  int m0, n0;
  gemm_tile(blockIdx.x, &m0, &n0);
  const int wave = t >> 6, lane = t & 63;
  const int wm = wave & 1, wn = wave >> 1;
  const int gq = lane >> 4, ln = lane & 15;

  f4 accK[2][4], accV[2][4];
#pragma unroll
  for (int i = 0; i < 2; ++i)
#pragma unroll
    for (int j = 0; j < 4; ++j) {
      accK[i][j] = (f4){0.f, 0.f, 0.f, 0.f};
      accV[i][j] = (f4){0.f, 0.f, 0.f, 0.f};
    }

  for (int k0 = 0; k0 < 1024; k0 += 32) {
    __syncthreads();
#pragma unroll
    for (int i = 0; i < 2; ++i) {  // A: shared by K and V
      int gid = t * 2 + i;
      int m = gid >> 2, g = gid & 3;
      size_t offA = (size_t)(m0 + m) * 1024 + k0 + g * 8;
      int slot = g * 1040 + m * 8;
      *(h8*)&Xb[0][slot] = *(const h8*)(Ah + offA);
      *(h8*)&Xb[1][slot] = *(const h8*)(Al + offA);
    }
    {  // W: 256 h8 per array, 4 arrays
      int n = t >> 2, g = t & 3;
      size_t offW = (size_t)(n0 + n) * 1024 + k0 + g * 8;
      int slot = g * 520 + n * 8;
      *(h8*)&WbK[0][slot] = *(const h8*)(Wthk + offW);
      *(h8*)&WbK[1][slot] = *(const h8*)(Wtlk + offW);
      *(h8*)&WbV[0][slot] = *(const h8*)(Wthv + offW);
      *(h8*)&WbV[1][slot] = *(const h8*)(Wtlv + offW);
    }
    __syncthreads();

    h8 bx[4][2];
#pragma unroll
    for (int mt = 0; mt < 4; ++mt)
#pragma unroll
      for (int s = 0; s < 2; ++s)
        bx[mt][s] = *(h8*)&Xb[s][gq * 1040 + (wm * 64 + mt * 16 + ln) * 8];

#pragma unroll
    for (int nt = 0; nt < 2; ++nt) {
      int wslot = gq * 520 + (wn * 32 + nt * 16 + ln) * 8;
      h8 awk0 = *(h8*)&WbK[0][wslot];
      h8 awk1 = *(h8*)&WbK[1][wslot];
      h8 awv0 = *(h8*)&WbV[0][wslot];
      h8 awv1 = *(h8*)&WbV[1][wslot];
#pragma unroll
      for (int mt = 0; mt < 4; ++mt) {
        const f4 z = (f4){0.f, 0.f, 0.f, 0.f};
        f4 a = accK[nt][mt];
        a = MFMA16(awk0, bx[mt][0], a);
        f4 t1 = MFMA16(awk0, bx[mt][1], z);
        t1 = MFMA16(awk1, bx[mt][0], t1);
        accK[nt][mt] = a + t1 * 4.8828125e-4f;

        f4 b = accV[nt][mt];
        b = MFMA16(awv0, bx[mt][0], b);
        f4 t2 = MFMA16(awv0, bx[mt][1], z);
        t2 = MFMA16(awv1, bx[mt][0], t2);
        accV[nt][mt] = b + t2 * 4.8828125e-4f;
      }
    }
  }
#pragma unroll
  for (int nt = 0; nt < 2; ++nt)
#pragma unroll
    for (int mt = 0; mt < 4; ++mt) {
      int m = m0 + wm * 64 + mt * 16 + ln;
      int n = n0 + wn * 32 + nt * 16 + gq * 4;
      int b = m >> 12, l = m & 4095, hh = n >> 6, d = n & 63;
      size_t o = (((size_t)(b * 16 + hh)) * 4096 + l) * 64 + d;
      f4 rk = accK[nt][mt] + *(const f4*)(bk + n);
      f4 rv = accV[nt][mt] + *(const f4*)(bv + n);
      h4 kh, kl, vh, vl;
#pragma unroll
      for (int j = 0; j < 4; ++j) {
        _Float16 p, q;
        split2(rk[j], &p, &q); kh[j] = p; kl[j] = q;
        split2(rv[j], &p, &q); vh[j] = p; vl[j] = q;
      }
      *(h4*)(Kh + o) = kh;
      *(h4*)(Kl + o) = kl;
      *(h4*)(Vh + o) = vh;
      *(h4*)(Vl + o) = vl;
    }
}

// ---------------------------------------------------------------------------
// init: cent0 = Q[:,:, :256, :] stored as split3; fused cnorm.
// (Cqg kept for update's empty-cluster reconstruction fidelity.)
// ---------------------------------------------------------------------------
__global__ __launch_bounds__(256) void init_cent_fused(const float* __restrict__ Q,
                                                       float* __restrict__ cnorm,
                                                       _Float16* __restrict__ Chg,
                                                       _Float16* __restrict__ Clg,
                                                       _Float16* __restrict__ Cqg) {
  const int gid = blockIdx.x * 4 + (threadIdx.x >> 6);  // bh*256+c
  const int bh = gid >> 8, c = gid & 255;
  const int lane = threadIdx.x & 63;
  float v = Q[((size_t)bh * 4096 + c) * 64 + lane];
  size_t ci = (size_t)gid * 64 + lane;
  _Float16 a, b, q;
  split3(v, &a, &b, &q);
  Chg[ci] = a; Clg[ci] = b; Cqg[ci] = q;
  float ss = v * v;
#pragma unroll
  for (int off = 1; off < 64; off <<= 1) ss += __shfl_xor(ss, off, 64);
  if (lane == 0) cnorm[gid] = ss;
}

// ---------------------------------------------------------------------------
// MFMA assign, 3-term distances, rt=4, grid 512, LDS-staged centroids
// (r17/r21-proven best; r22 showed LDS-free direct-global B-frags are
// 128B-stride uncoalesced and regress badly).
// ---------------------------------------------------------------------------
__global__ __launch_bounds__(256) void assign_mfma(const _Float16* __restrict__ Qh,
                                                   const _Float16* __restrict__ Ql,
                                                   const _Float16* __restrict__ Chg,
                                                   const _Float16* __restrict__ Clg,
                                                   const float* __restrict__ cnorm,
                                                   int* __restrict__ assign,
                                                   unsigned* __restrict__ mask) {
  __shared__ _Float16 CS0[8320], CS1[8320];  // 8 slabs x 1040
  __shared__ float cn[128];
  const int t = threadIdx.x;
  const int wave = t >> 6, lane = t & 63;
  const int bh = blockIdx.x & 31, lch = blockIdx.x >> 5;  // lch 0..15
  const int l0 = lch * 256;
  const int gq = lane >> 4, ln = lane & 15;

  // A-frags: this wave's 64 Q rows (pure loads)
  h8 ah[4][2], al[4][2];
#pragma unroll
  for (int rt = 0; rt < 4; ++rt)
#pragma unroll
    for (int ks = 0; ks < 2; ++ks) {
      size_t off =
          ((size_t)bh * 4096 + l0 + wave * 64 + rt * 16 + ln) * 64 + ks * 32 + gq * 8;
      ah[rt][ks] = *(const h8*)(Qh + off);
      al[rt][ks] = *(const h8*)(Ql + off);
    }

  float bestv[4][4];
  int bestc[4][4];
#pragma unroll
  for (int rt = 0; rt < 4; ++rt)
#pragma unroll
    for (int j = 0; j < 4; ++j) { bestv[rt][j] = 3.4e38f; bestc[rt][j] = 0; }

  for (int half = 0; half < 2; ++half) {
    __syncthreads();
#pragma unroll
    for (int i = 0; i < 4; ++i) {
      int gid = t * 4 + i;
      int c = gid >> 3, g = gid & 7;
      size_t src = ((size_t)(bh * 256 + half * 128 + c)) * 64 + g * 8;
      int dst = g * 1040 + c * 8;
      *(h8*)&CS0[dst] = *(const h8*)(Chg + src);
      *(h8*)&CS1[dst] = *(const h8*)(Clg + src);
    }
    if (t < 128) cn[t] = cnorm[bh * 256 + half * 128 + t];
    __syncthreads();

#pragma unroll
    for (int ct = 0; ct < 8; ++ct) {
      const f4 z = (f4){0.f, 0.f, 0.f, 0.f};
      f4 a0[4] = {z, z, z, z}, a1[4] = {z, z, z, z};
#pragma unroll
      for (int ks = 0; ks < 2; ++ks) {
        int bslot = (ks * 4 + gq) * 1040 + (ct * 16 + ln) * 8;
        h8 bh_ = *(h8*)&CS0[bslot];
        h8 bl_ = *(h8*)&CS1[bslot];
#pragma unroll
        for (int rt = 0; rt < 4; ++rt) {
          a0[rt] = MFMA16(ah[rt][ks], bh_, a0[rt]);
          a1[rt] = MFMA16(ah[rt][ks], bl_, a1[rt]);
          a1[rt] = MFMA16(al[rt][ks], bh_, a1[rt]);
        }
      }
      float cnv = cn[ct * 16 + ln];
      int cbase = half * 128 + ct * 16 + ln;
#pragma unroll
      for (int rt = 0; rt < 4; ++rt) {
        f4 dot = a0[rt] + a1[rt] * 4.8828125e-4f;
#pragma unroll
        for (int j = 0; j < 4; ++j) {
          float dist = fmaf(-2.f, dot[j], cnv);
          if (dist < bestv[rt][j]) { bestv[rt][j] = dist; bestc[rt][j] = cbase; }
        }
      }
    }
  }
#pragma unroll
  for (int rt = 0; rt < 4; ++rt)
#pragma unroll
    for (int j = 0; j < 4; ++j) {
      float v = bestv[rt][j];
      int c = bestc[rt][j];
#pragma unroll
      for (int off = 1; off < 16; off <<= 1) {
        float ov = __shfl_xor(v, off, 64);
        int oc = __shfl_xor(c, off, 64);
        if (ov < v || (ov == v && oc < c)) { v = ov; c = oc; }
      }
      if (ln == 0) {
        int l = l0 + wave * 64 + rt * 16 + gq * 4 + j;
        assign[(size_t)bh * 4096 + l] = c;
        atomicOr(&mask[(((size_t)bh * 256 + c) << 7) + (l >> 5)], 1u << (l & 31));
      }
    }
}

// ---------------------------------------------------------------------------
// centroid update, 4-way wave-parallel scan (r18-proven). Clears mask;
// fused cnorm + split3. Reads fp32 Q.
// ---------------------------------------------------------------------------
__global__ __launch_bounds__(256) void update4_kernel(const float* __restrict__ Q,
                                                      unsigned* __restrict__ mask,
                                                      float* __restrict__ cnorm,
                                                      _Float16* __restrict__ Chg,
                                                      _Float16* __restrict__ Clg,
                                                      _Float16* __restrict__ Cqg) {
  const int gid = blockIdx.x;           // bh*256+c
  const int bh = gid >> 8;
  const int t = threadIdx.x;
  const int wave = t >> 6, lane = t & 63;
  __shared__ unsigned w[128];
  __shared__ float psum[4][64];
  __shared__ int pcnt[4];
  unsigned* mp = mask + ((size_t)gid << 7);
  if (t < 128) {
    w[t] = mp[t];
    mp[t] = 0u;  // self-restoring for next iteration / next call
  }
  __syncthreads();
  float sum = 0.f;
  int cnt = 0;
  const float* qb = Q + (size_t)bh * 4096 * 64 + lane;
  const int i0 = wave * 32;
  for (int i = i0; i < i0 + 32; ++i) {
    unsigned u = w[i];
    while (u) {  // wave-uniform
      int b = __ffs(u) - 1;
      u &= u - 1;
      int l = i * 32 + b;
      sum += qb[(size_t)l * 64];
      ++cnt;
    }
  }
  psum[wave][lane] = sum;
  if (lane == 0) pcnt[wave] = cnt;
  __syncthreads();
  if (wave == 0) {
    int total = (pcnt[0] + pcnt[1]) + (pcnt[2] + pcnt[3]);
    size_t ci = (size_t)gid * 64 + lane;
    float v;
    if (total) {
      float s = (psum[0][lane] + psum[1][lane]) + (psum[2][lane] + psum[3][lane]);
      v = s / (float)total;
    } else {
      v = (float)Chg[ci] + (float)Clg[ci] * 4.8828125e-4f +
          (float)Cqg[ci] * 2.384185791015625e-7f;
    }
    _Float16 a, b2, q;
    split3(v, &a, &b2, &q);
    Chg[ci] = a; Clg[ci] = b2; Cqg[ci] = q;
    float ss = v * v;
#pragma unroll
    for (int off = 1; off < 64; off <<= 1) ss += __shfl_xor(ss, off, 64);
    if (lane == 0) cnorm[gid] = ss;
  }
}

// ---------------------------------------------------------------------------
// MFMA flash attention. 16 uniform chunks of 4x64 l-tiles; grid 512.
// ---------------------------------------------------------------------------
#define NCH 16
__global__ __launch_bounds__(256) void attn_mfma(const _Float16* __restrict__ Kh,
                                                 const _Float16* __restrict__ Kl,
                                                 const _Float16* __restrict__ Vh,
                                                 const _Float16* __restrict__ Vl,
                                                 const _Float16* __restrict__ Chg,
                                                 const _Float16* __restrict__ Clg,
                                                 float* __restrict__ pacc,
                                                 float* __restrict__ pml) {
  __shared__ _Float16 KhS[4160], KlS[4160];    // 8 slabs x 520
  __shared__ _Float16 VhT[64 * 72], VlT[64 * 72];
  __shared__ _Float16 Ph[4][16 * 72], Pl[4][16 * 72];
  const int bh = blockIdx.x & 31, ch = blockIdx.x >> 5;  // ch 0..15
  const int t = threadIdx.x;
  const int wave = t >> 6, lane = t & 63, gq = lane >> 4, ln = lane & 15;

  h8 cah[4][2], cal[4][2];
#pragma unroll
  for (int cb = 0; cb < 4; ++cb)
#pragma unroll
    for (int ks = 0; ks < 2; ++ks) {
      size_t off = ((size_t)bh * 256 + wave * 64 + cb * 16 + ln) * 64 + ks * 32 + gq * 8;
      cah[cb][ks] = *(const h8*)(Chg + off);
      cal[cb][ks] = *(const h8*)(Clg + off);
    }

  f4 mr[4], ls[4], acc[4][4];
#pragma unroll
  for (int cb = 0; cb < 4; ++cb) {
    mr[cb] = (f4){-3.0e38f, -3.0e38f, -3.0e38f, -3.0e38f};
    ls[cb] = (f4){0.f, 0.f, 0.f, 0.f};
#pragma unroll
    for (int dt = 0; dt < 4; ++dt) acc[cb][dt] = (f4){0.f, 0.f, 0.f, 0.f};
  }

  for (int lt = 0; lt < 4; ++lt) {
    const int l0 = (ch * 4 + lt) * 64;
    __syncthreads();
#pragma unroll
    for (int i = 0; i < 2; ++i) {  // stage K (h8 copies) + V (transposed)
      int gid = t * 2 + i;
      int l = gid >> 3, g = gid & 7;
      size_t src = ((size_t)bh * 4096 + l0 + l) * 64 + g * 8;
      int dst = g * 520 + l * 8;
      *(h8*)&KhS[dst] = *(const h8*)(Kh + src);
      *(h8*)&KlS[dst] = *(const h8*)(Kl + src);
      h8 vh = *(const h8*)(Vh + src);
      h8 vl = *(const h8*)(Vl + src);
#pragma unroll
      for (int j = 0; j < 8; ++j) {
        VhT[(g * 8 + j) * 72 + l] = vh[j];
        VlT[(g * 8 + j) * 72 + l] = vl[j];
      }
    }
    __syncthreads();

#pragma unroll
    for (int cb = 0; cb < 4; ++cb) {
      // ---- QK^T: S rows c (=gq*4+j), cols l (=st*16+ln)
      f4 s[4];
#pragma unroll
      for (int st = 0; st < 4; ++st) {
        const f4 z = (f4){0.f, 0.f, 0.f, 0.f};
        f4 a0 = z, a1 = z;
#pragma unroll
        for (int ks = 0; ks < 2; ++ks) {
          int bslot = (ks * 4 + gq) * 520 + (st * 16 + ln) * 8;
          h8 kbh = *(h8*)&KhS[bslot];
          h8 kbl = *(h8*)&KlS[bslot];
          a0 = MFMA16(cah[cb][ks], kbh, a0);
          a1 = MFMA16(cah[cb][ks], kbl, a1);
          a1 = MFMA16(cal[cb][ks], kbh, a1);
        }
        s[st] = (a0 + a1 * 4.8828125e-4f) * 0.125f;
      }
      // ---- online softmax (per c = gq*4+j)
      f4 ml;
#pragma unroll
      for (int j = 0; j < 4; ++j)
        ml[j] = fmaxf(fmaxf(s[0][j], s[1][j]), fmaxf(s[2][j], s[3][j]));
#pragma unroll
      for (int off = 1; off < 16; off <<= 1)
#pragma unroll
        for (int j = 0; j < 4; ++j) ml[j] = fmaxf(ml[j], __shfl_xor(ml[j], off, 64));
      f4 mn, corr;
#pragma unroll
      for (int j = 0; j < 4; ++j) {
        mn[j] = fmaxf(mr[cb][j], ml[j]);
        corr[j] = __expf(mr[cb][j] - mn[j]);
      }
      f4 psum = (f4){0.f, 0.f, 0.f, 0.f};
#pragma unroll
      for (int st = 0; st < 4; ++st) {
#pragma unroll
        for (int j = 0; j < 4; ++j) {
          float p = __expf(s[st][j] - mn[j]);
          psum[j] += p;
          _Float16 a, b;
          split2(p, &a, &b);
          Ph[wave][(gq * 4 + j) * 72 + st * 16 + ln] = a;
          Pl[wave][(gq * 4 + j) * 72 + st * 16 + ln] = b;
        }
      }
#pragma unroll
      for (int off = 1; off < 16; off <<= 1)
#pragma unroll
        for (int j = 0; j < 4; ++j) psum[j] += __shfl_xor(psum[j], off, 64);
      ls[cb] = ls[cb] * corr + psum;
      mr[cb] = mn;
#pragma unroll
      for (int dt = 0; dt < 4; ++dt) acc[cb][dt] *= corr;
      // ---- PV (same-wave LDS handoff)
#pragma unroll
      for (int ks = 0; ks < 2; ++ks) {
        h8 pah = *(h8*)&Ph[wave][ln * 72 + ks * 32 + gq * 8];
        h8 pal = *(h8*)&Pl[wave][ln * 72 + ks * 32 + gq * 8];
#pragma unroll
        for (int dt = 0; dt < 4; ++dt) {
          int vslot = (dt * 16 + ln) * 72 + ks * 32 + gq * 8;
          h8 vbh = *(h8*)&VhT[vslot];
          h8 vbl = *(h8*)&VlT[vslot];
          acc[cb][dt] = MFMA16(pah, vbh, acc[cb][dt]);
          const f4 z = (f4){0.f, 0.f, 0.f, 0.f};
          f4 t1 = MFMA16(pah, vbl, z);
          t1 = MFMA16(pal, vbh, t1);
          acc[cb][dt] += t1 * 4.8828125e-4f;
        }
      }
    }
  }
  // ---- write partials
#pragma unroll
  for (int cb = 0; cb < 4; ++cb) {
    int crow = wave * 64 + cb * 16 + gq * 4;
#pragma unroll
    for (int dt = 0; dt < 4; ++dt)
#pragma unroll
      for (int j = 0; j < 4; ++j)
        pacc[((size_t)ch * 8192 + bh * 256 + crow + j) * 64 + dt * 16 + ln] = acc[cb][dt][j];
    if (ln == 0) {
#pragma unroll
      for (int j = 0; j < 4; ++j) {
        size_t r = (size_t)ch * 8192 + bh * 256 + crow + j;
        pml[r * 2 + 0] = mr[cb][j];
        pml[r * 2 + 1] = ls[cb][j];
      }
    }
  }
}

// ---------------------------------------------------------------------------
// merge 16 chunk-partials -> Oc[bh*256+c][64]
// ---------------------------------------------------------------------------
__global__ __launch_bounds__(256) void merge_kernel(const float* __restrict__ pacc,
                                                    const float* __restrict__ pml,
                                                    float* __restrict__ Oc) {
  const int row = blockIdx.x * 4 + (threadIdx.x >> 6);
  const int lane = threadIdx.x & 63;
  float M = -3.0e38f;
#pragma unroll
  for (int q = 0; q < NCH; ++q) M = fmaxf(M, pml[((size_t)q * 8192 + row) * 2]);
  float S = 0.f, o = 0.f;
#pragma unroll
  for (int q = 0; q < NCH; ++q) {
    size_t r = (size_t)q * 8192 + row;
    float w = __expf(pml[r * 2] - M);
    S = fmaf(w, pml[r * 2 + 1], S);
    o = fmaf(w, pacc[r * 64 + lane], o);
  }
  Oc[(size_t)row * 64 + lane] = o / S;
}

// ---------------------------------------------------------------------------
// gather + split2: Oh/Ol[b][l][h*64+d] = split2(Oc[b][h][assign[b][h][l]][d])
// ---------------------------------------------------------------------------
__global__ void gather_kernel(const float* __restrict__ Oc,
                              const int* __restrict__ assign,
                              _Float16* __restrict__ Oh,
                              _Float16* __restrict__ Ol) {
  size_t idx = (size_t)blockIdx.x * 256 + threadIdx.x;
  int d4 = (int)(idx & 15) * 4;
  size_t rest = idx >> 4;
  int h = (int)(rest & 15);
  size_t bl = rest >> 4;
  int b = (int)(bl >> 12);
  int l = (int)(bl & 4095);
  int bh = b * 16 + h;
  int a = assign[(size_t)bh * 4096 + l];
  float4 v = *(const float4*)(Oc + (((size_t)bh * 256 + a) * 64 + d4));
  float xs[4] = {v.x, v.y, v.z, v.w};
  h4 vh, vl;
#pragma unroll
  for (int j = 0; j < 4; ++j) {
    _Float16 p, q;
    split2(xs[j], &p, &q);
    vh[j] = p; vl[j] = q;
  }
  size_t o = bl * 1024 + (size_t)h * 64 + d4;
  *(h4*)(Oh + o) = vh;
  *(h4*)(Ol + o) = vl;
}

// ---------------------------------------------------------------------------
extern "C" void kernel_launch(void* const* d_in, const int* in_sizes, int n_in,
                              void* d_out, int out_size, void* d_ws, size_t ws_size,
                              hipStream_t stream) {
  const float* X  = (const float*)d_in[0];
  const float* Wq = (const float*)d_in[3];
  const float* bq = (const float*)d_in[4];
  const float* Wk = (const float*)d_in[5];
  const float* bk = (const float*)d_in[6];
  const float* Wv = (const float*)d_in[7];
  const float* bv = (const float*)d_in[8];
  const float* Wo = (const float*)d_in[9];
  const float* bo = (const float*)d_in[10];
  float* out = (float*)d_out;

  // ---- Workspace (floats), total 26,353,664 == proven budget (r19 layout).
  // R1 [0, 8,388,608):  A-B: Q fp32 | C: Wthk/Wtlk/Wthv/Wtlv | D: pacc
  // R2 [8,388,608, 16,777,216): A: WthQ/WtlQ@0 + Qh@+1,048,576 (A-B) |
  //                             C-D: Kh/Kl | E: Oh/Ol
  // R3 [16,777,216, 25,165,824): A-B: Ql@0 | B: mask@+4,194,304 | C-D: Vh/Vl |
  //                              D-E: Oc@0 | E: Wth3/Wtl3@+524,288
  // R4 [25,165,824, 26,353,664): cnorm | assign | Chg | Clg | Cqg | pml
  // d_out (8,388,608 fl = 16,777,216 halfs): A-C: Xh/Xl | E: final output.
  float* W0 = (float*)d_ws;
  float* R1 = W0;
  float* R2 = W0 + 8388608;
  float* R3 = W0 + 16777216;
  float* R4 = W0 + 25165824;

  _Float16* Xh = (_Float16*)out;                  // 8,388,608 halfs
  _Float16* Xl = (_Float16*)out + 8388608;        // 8,388,608 halfs

  float* Q = R1;
  _Float16* WthQ = (_Float16*)R2;
  _Float16* WtlQ = (_Float16*)(R2 + 524288);
  _Float16* Qh = (_Float16*)(R2 + 1048576);       // A-B (written by MODE-4 gemm)
  _Float16* Ql = (_Float16*)R3;                   // A-B

  float* cnorm = R4;                              // 8,192
  int* assign  = (int*)(R4 + 8192);               // 131,072
  _Float16* Chg = (_Float16*)(R4 + 139264);       // 524,288 halfs
  _Float16* Clg = (_Float16*)(R4 + 401408);
  _Float16* Cqg = (_Float16*)(R4 + 663552);
  float* pml    = R4 + 925696;                    // 16*8192*2 = 262,144
  unsigned* mask = (unsigned*)(R3 + 4194304);     // 1,048,576 words (phase B)

  _Float16* Wthk = (_Float16*)R1;                 // phase C (Q dead)
  _Float16* Wtlk = (_Float16*)(R1 + 524288);
  _Float16* Wthv = (_Float16*)(R1 + 1048576);
  _Float16* Wtlv = (_Float16*)(R1 + 1572864);
  _Float16* Kh = (_Float16*)R2;                   // C -> D (WthQ/Qh dead)
  _Float16* Kl = (_Float16*)(R2 + 4194304);
  _Float16* Vh = (_Float16*)R3;                   // C -> D (Ql, mask dead)
  _Float16* Vl = (_Float16*)(R3 + 4194304);

  float* pacc = R1;                               // D
  float* Oc   = R3;                               // D -> E (Vh dead)

  _Float16* Oh = (_Float16*)R2;                   // E (Kh/Kl dead)
  _Float16* Ol = (_Float16*)(R2 + 4194304);
  _Float16* Wth3 = (_Float16*)(R3 + 524288);      // E (after Oc)
  _Float16* Wtl3 = (_Float16*)(R3 + 1048576);

  dim3 tgrid(32, 32);
  dim3 ggrid(64, 16);                              // 128x64 tiles -> 1024 blocks
  size_t smem2 = (size_t)(2 * 4160 + 2 * 2080) * sizeof(_Float16);  // 24,960 B

  // Phase A: pre-split X (2-way); Q projection (SPLITS=2, MODE 4: also emits
  // Qh/Ql split2 halves in the epilogue -> xsplit2(Q) pass eliminated).
  xsplit2_kernel<<<8192, 256, 0, stream>>>(X, Xh, Xl);
  tsplit_kernel<<<tgrid, 256, 0, stream>>>(Wq, WthQ, WtlQ, nullptr);
  gemm_pre<2, 4><<<ggrid, 256, smem2, stream>>>(Xh, Xl, nullptr, WthQ, WtlQ, nullptr,
                                                bq, Q, Qh, Ql);

  // Phase B: k-means (11 assign/update rounds); assign rt=4; update 4-wave
  init_cent_fused<<<2048, 256, 0, stream>>>(Q, cnorm, Chg, Clg, Cqg);
  hipMemsetAsync(mask, 0, 1048576 * sizeof(unsigned), stream);
  for (int it = 0; it < 11; ++it) {
    assign_mfma<<<512, 256, 0, stream>>>(Qh, Ql, Chg, Clg, cnorm, assign, mask);
    update4_kernel<<<8192, 256, 0, stream>>>(Q, mask, cnorm, Chg, Clg, Cqg);
  }

  // Phase C: fused K+V projection (XCD-swizzled); single fused W-transpose.
  tsplit_kv_kernel<<<tgrid, 256, 0, stream>>>(Wk, Wv, Wthk, Wtlk, Wthv, Wtlv);
  gemm_kv<<<1024, 256, 0, stream>>>(Xh, Xl, Wthk, Wtlk, Wthv, Wtlv, bk, bv,
                                    Kh, Kl, Vh, Vl);

  // Phase D: clustered attention (16 uniform L-chunks) + merge
  attn_mfma<<<512, 256, 0, stream>>>(Kh, Kl, Vh, Vl, Chg, Clg, pacc, pml);
  merge_kernel<<<2048, 256, 0, stream>>>(pacc, pml, Oc);

  // Phase E: gather (emits split2) + output projection
  gather_kernel<<<8192, 256, 0, stream>>>(Oc, assign, Oh, Ol);
  tsplit_kernel<<<tgrid, 256, 0, stream>>>(Wo, Wth3, Wtl3, nullptr);
  gemm_pre<2, 0><<<ggrid, 256, smem2, stream>>>(Oh, Ol, nullptr, Wth3, Wtl3, nullptr, bo,
                                                out, nullptr, nullptr);
}

// Round 24
// 1102.913 us; speedup vs baseline: 1.3432x; 1.0273x over previous
//
#include <hip/hip_runtime.h>
#include <cstddef>

// B=2, L=4096, HID=1024, H=16, D=64, C=256, KM_ITERS=10 (11 assign/update rounds)
// BH=32, M=B*L=8192

typedef _Float16 h8 __attribute__((ext_vector_type(8)));
typedef _Float16 h4 __attribute__((ext_vector_type(4)));
typedef float f4 __attribute__((ext_vector_type(4)));

#define MFMA16(a, b, c) __builtin_amdgcn_mfma_f32_16x16x32_f16((a), (b), (c), 0, 0, 0)

// Async global->LDS 16B DMA (m97 pattern). Dest is wave-linear: lane l's 16B
// lands at base + l*16; we pass the per-lane address matching that layout.
__device__ __forceinline__ void gload16(const _Float16* gsrc, _Float16* ldst) {
  __builtin_amdgcn_global_load_lds(
      (__attribute__((address_space(1))) void*)gsrc,
      (__attribute__((address_space(3))) void*)ldst, 16, 0, 0);
}

// fp32 -> f16 splits. lo scaled by 2^11, quad term by 2^22 (avoids f16 subnormals).
__device__ __forceinline__ void split3(float x, _Float16* h, _Float16* l, _Float16* q) {
  _Float16 hh = (_Float16)x;
  float r1 = x - (float)hh;
  _Float16 ll = (_Float16)(r1 * 2048.0f);
  float r2 = fmaf((float)ll, -4.8828125e-4f, r1);
  *h = hh; *l = ll; *q = (_Float16)(r2 * 4194304.0f);
}
__device__ __forceinline__ void split2(float x, _Float16* h, _Float16* l) {
  _Float16 hh = (_Float16)x;
  float r1 = x - (float)hh;
  *h = hh; *l = (_Float16)(r1 * 2048.0f);
}

// ---------------------------------------------------------------------------
// elementwise split2 of an 8,388,608-float array (X only now).
// ---------------------------------------------------------------------------
__global__ __launch_bounds__(256) void xsplit2_kernel(const float* __restrict__ X,
                                                      _Float16* __restrict__ xh,
                                                      _Float16* __restrict__ xl) {
  size_t i = ((size_t)blockIdx.x * 256 + threadIdx.x) * 4;
  float4 v = *(const float4*)(X + i);
  float xs[4] = {v.x, v.y, v.z, v.w};
  h4 vh, vl;
#pragma unroll
  for (int j = 0; j < 4; ++j) {
    _Float16 a, b;
    split2(xs[j], &a, &b);
    vh[j] = a; vl[j] = b;
  }
  *(h4*)(xh + i) = vh;
  *(h4*)(xl + i) = vl;
}

// ---------------------------------------------------------------------------
// W[1024][1024] -> Wt_h/l/q[n][k] (transposed + split). tq may be null.
// ---------------------------------------------------------------------------
__global__ __launch_bounds__(256) void tsplit_kernel(const float* __restrict__ W,
                                                     _Float16* __restrict__ th,
                                                     _Float16* __restrict__ tl,
                                                     _Float16* __restrict__ tq) {
  __shared__ float tile[32][33];
  const int n0 = blockIdx.x * 32, k0 = blockIdx.y * 32;
  const int tx = threadIdx.x & 31, ty = threadIdx.x >> 5;
#pragma unroll
  for (int i = 0; i < 4; ++i) {
    int k = ty + i * 8;
    tile[k][tx] = W[(size_t)(k0 + k) * 1024 + n0 + tx];
  }
  __syncthreads();
#pragma unroll
  for (int i = 0; i < 4; ++i) {
    int n = ty + i * 8;
    float x = tile[tx][n];
    _Float16 h, l, q;
    split3(x, &h, &l, &q);
    size_t o = (size_t)(n0 + n) * 1024 + k0 + tx;
    th[o] = h; tl[o] = l;
    if (tq) tq[o] = q;
  }
}

// ---------------------------------------------------------------------------
// Fused transpose+split of BOTH Wk and Wv in one launch (r19-proven).
// ---------------------------------------------------------------------------
__global__ __launch_bounds__(256) void tsplit_kv_kernel(const float* __restrict__ Wk,
                                                        const float* __restrict__ Wv,
                                                        _Float16* __restrict__ thk,
                                                        _Float16* __restrict__ tlk,
                                                        _Float16* __restrict__ thv,
                                                        _Float16* __restrict__ tlv) {
  __shared__ float tk[32][33];
  __shared__ float tv[32][33];
  const int n0 = blockIdx.x * 32, k0 = blockIdx.y * 32;
  const int tx = threadIdx.x & 31, ty = threadIdx.x >> 5;
#pragma unroll
  for (int i = 0; i < 4; ++i) {
    int k = ty + i * 8;
    tk[k][tx] = Wk[(size_t)(k0 + k) * 1024 + n0 + tx];
    tv[k][tx] = Wv[(size_t)(k0 + k) * 1024 + n0 + tx];
  }
  __syncthreads();
#pragma unroll
  for (int i = 0; i < 4; ++i) {
    int n = ty + i * 8;
    size_t o = (size_t)(n0 + n) * 1024 + k0 + tx;
    _Float16 h, l;
    split2(tk[tx][n], &h, &l);
    thk[o] = h; tlk[o] = l;
    split2(tv[tx][n], &h, &l);
    thv[o] = h; tlv[o] = l;
  }
}

// XCD-aware bijective remap for the 1024-block fused KV gemm (1024 = 8 x 128),
// n-fast within each XCD chunk (r11 measured win on gemm_kv; r20 showed it
// HURTS the Q/O gemms, so it stays KV-only).
__device__ __forceinline__ void gemm_tile(int bid, int* m0, int* n0) {
  int nb = ((bid & 7) << 7) | (bid >> 3);
  *m0 = (nb >> 4) * 128;
  *n0 = (nb & 15) * 64;
}

// ---------------------------------------------------------------------------
// Pre-split MFMA GEMM, r24: global_load_lds width-16 staging (m97 lever).
// LDS layout row-interleaved: A slot = m*32 + g*8 halves, W slot = n*32 + g*8
// (matches global k-order -> DMA's base+lane*16B dest is exact; global src is
// 128B-contiguous per 4-lane group -> coalesced). Tile 128x64, BK=32,
// 2-D grid (64,16), __launch_bounds__(256,4). Same data -> same MFMA order ->
// bit-identical numerics vs r21.
// MODE 0: fp32 out[m][n]. MODE 4: fp32 QKV layout AND split2 halves -> oh/ol.
// ---------------------------------------------------------------------------
template <int SPLITS, int MODE>
__global__ __launch_bounds__(256, 4) void gemm_pre(const _Float16* __restrict__ Ah,
                                                   const _Float16* __restrict__ Al,
                                                   const _Float16* __restrict__ Aq,
                                                   const _Float16* __restrict__ Wth,
                                                   const _Float16* __restrict__ Wtl,
                                                   const _Float16* __restrict__ Wtq,
                                                   const float* __restrict__ bias,
                                                   float* __restrict__ outF,
                                                   _Float16* __restrict__ oh,
                                                   _Float16* __restrict__ ol) {
  extern __shared__ _Float16 sm[];
  _Float16* Xb[3];
  _Float16* Wb[3];
  for (int s = 0; s < SPLITS; ++s) {
    Xb[s] = sm + s * 4096;                 // A: 128 rows x 32 halves
    Wb[s] = sm + SPLITS * 4096 + s * 2048; // W: 64 rows x 32 halves
  }
  const int t = threadIdx.x;
  const int m0 = blockIdx.x * 128, n0 = blockIdx.y * 64;
  const int wave = t >> 6, lane = t & 63;
  const int wm = wave & 1, wn = wave >> 1;  // wn 0..1
  const int gq = lane >> 4, ln = lane & 15;
  const int mg = lane >> 2, gg = lane & 3;  // DMA lane map: row-sub, k-subslot

  f4 acc[2][4];
#pragma unroll
  for (int i = 0; i < 2; ++i)
#pragma unroll
    for (int j = 0; j < 4; ++j) acc[i][j] = (f4){0.f, 0.f, 0.f, 0.f};

  for (int k0 = 0; k0 < 1024; k0 += 32) {
    __syncthreads();
    // ---- A: per split 8 chunks of 64 slots; wave w stages chunks {2w,2w+1}
#pragma unroll
    for (int i = 0; i < 2; ++i) {
      int c = wave * 2 + i;
      int m = c * 16 + mg;
      size_t offA = (size_t)(m0 + m) * 1024 + k0 + gg * 8;
      int dst = c * 512 + lane * 8;
      gload16(Ah + offA, Xb[0] + dst);
      gload16(Al + offA, Xb[1] + dst);
      if (SPLITS == 3) gload16(Aq + offA, Xb[2] + dst);
    }
    {  // ---- W: per split 4 chunks; wave w stages chunk w
      int n = wave * 16 + mg;
      size_t offW = (size_t)(n0 + n) * 1024 + k0 + gg * 8;
      int dst = wave * 512 + lane * 8;
      gload16(Wth + offW, Wb[0] + dst);
      gload16(Wtl + offW, Wb[1] + dst);
      if (SPLITS == 3) gload16(Wtq + offW, Wb[2] + dst);
    }
    __syncthreads();

    h8 bx[4][3];
#pragma unroll
    for (int mt = 0; mt < 4; ++mt)
#pragma unroll
      for (int s = 0; s < SPLITS; ++s)
        bx[mt][s] = *(h8*)&Xb[s][(wm * 64 + mt * 16 + ln) * 32 + gq * 8];

#pragma unroll
    for (int nt = 0; nt < 2; ++nt) {
      h8 aw[3];
#pragma unroll
      for (int s = 0; s < SPLITS; ++s)
        aw[s] = *(h8*)&Wb[s][(wn * 32 + nt * 16 + ln) * 32 + gq * 8];
#pragma unroll
      for (int mt = 0; mt < 4; ++mt) {
        const f4 z = (f4){0.f, 0.f, 0.f, 0.f};
        f4 a = acc[nt][mt];
        a = MFMA16(aw[0], bx[mt][0], a);
        f4 t1 = MFMA16(aw[0], bx[mt][1], z);
        t1 = MFMA16(aw[1], bx[mt][0], t1);
        if (SPLITS == 3) {
          f4 t2 = MFMA16(aw[0], bx[mt][2], z);
          t2 = MFMA16(aw[1], bx[mt][1], t2);
          t2 = MFMA16(aw[2], bx[mt][0], t2);
          a += t1 * 4.8828125e-4f + t2 * 2.384185791015625e-7f;
        } else {
          a += t1 * 4.8828125e-4f;
        }
        acc[nt][mt] = a;
      }
    }
  }
#pragma unroll
  for (int nt = 0; nt < 2; ++nt)
#pragma unroll
    for (int mt = 0; mt < 4; ++mt) {
      int m = m0 + wm * 64 + mt * 16 + ln;
      int n = n0 + wn * 32 + nt * 16 + gq * 4;
      f4 r = acc[nt][mt] + *(const f4*)(bias + n);
      if (MODE == 0) {
        *(f4*)(outF + (size_t)m * 1024 + n) = r;
      } else {
        int b = m >> 12, l = m & 4095, hh = n >> 6, d = n & 63;
        size_t o = (((size_t)(b * 16 + hh)) * 4096 + l) * 64 + d;
        *(f4*)(outF + o) = r;
        if (MODE == 4) {  // also emit split2 halves (bit-identical to xsplit2)
          h4 vh, vl;
#pragma unroll
          for (int j = 0; j < 4; ++j) {
            _Float16 a2, b2;
            split2(r[j], &a2, &b2);
            vh[j] = a2; vl[j] = b2;
          }
          *(h4*)(oh + o) = vh;
          *(h4*)(ol + o) = vl;
        }
      }
    }
}

// ---------------------------------------------------------------------------
// Fused K+V projection (r10 core + r11 XCD swizzle + r24 global_load_lds).
// ---------------------------------------------------------------------------
__global__ __launch_bounds__(256, 4) void gemm_kv(const _Float16* __restrict__ Ah,
                                                  const _Float16* __restrict__ Al,
                                                  const _Float16* __restrict__ Wthk,
                                                  const _Float16* __restrict__ Wtlk,
                                                  const _Float16* __restrict__ Wthv,
                                                  const _Float16* __restrict__ Wtlv,
                                                  const float* __restrict__ bk,
                                                  const float* __restrict__ bv,
                                                  _Float16* __restrict__ Kh,
                                                  _Float16* __restrict__ Kl,
                                                  _Float16* __restrict__ Vh,
                                                  _Float16* __restrict__ Vl) {
  __shared__ _Float16 sm[2 * 4096 + 4 * 2048];   // 32,768 B
  _Float16* Xb[2] = {sm, sm + 4096};
  _Float16* WbK[2] = {sm + 8192, sm + 8192 + 2048};
  _Float16* WbV[2] = {sm + 8192 + 4096, sm + 8192 + 4096 + 2048};
  const int t = threadIdx.x;
  int m0, n0;
  gemm_tile(blockIdx.x, &m0, &n0);
  const int wave = t >> 6, lane = t & 63;
  const int wm = wave & 1, wn = wave >> 1;
  const int gq = lane >> 4, ln = lane & 15;
  const int mg = lane >> 2, gg = lane & 3;

  f4 accK[2][4], accV[2][4];
#pragma unroll
  for (int i = 0; i < 2; ++i)
#pragma unroll
    for (int j = 0; j < 4; ++j) {
      accK[i][j] = (f4){0.f, 0.f, 0.f, 0.f};
      accV[i][j] = (f4){0.f, 0.f, 0.f, 0.f};
    }

  for (int k0 = 0; k0 < 1024; k0 += 32) {
    __syncthreads();
#pragma unroll
    for (int i = 0; i < 2; ++i) {  // A: shared by K and V
      int c = wave * 2 + i;
      int m = c * 16 + mg;
      size_t offA = (size_t)(m0 + m) * 1024 + k0 + gg * 8;
      int dst = c * 512 + lane * 8;
      gload16(Ah + offA, Xb[0] + dst);
      gload16(Al + offA, Xb[1] + dst);
    }
    {  // W: 4 arrays, wave w stages chunk w of each
      int n = wave * 16 + mg;
      size_t offW = (size_t)(n0 + n) * 1024 + k0 + gg * 8;
      int dst = wave * 512 + lane * 8;
      gload16(Wthk + offW, WbK[0] + dst);
      gload16(Wtlk + offW, WbK[1] + dst);
      gload16(Wthv + offW, WbV[0] + dst);
      gload16(Wtlv + offW, WbV[1] + dst);
    }
    __syncthreads();

    h8 bx[4][2];
#pragma unroll
    for (int mt = 0; mt < 4; ++mt)
#pragma unroll
      for (int s = 0; s < 2; ++s)
        bx[mt][s] = *(h8*)&Xb[s][(wm * 64 + mt * 16 + ln) * 32 + gq * 8];

#pragma unroll
    for (int nt = 0; nt < 2; ++nt) {
      int wslot = (wn * 32 + nt * 16 + ln) * 32 + gq * 8;
      h8 awk0 = *(h8*)&WbK[0][wslot];
      h8 awk1 = *(h8*)&WbK[1][wslot];
      h8 awv0 = *(h8*)&WbV[0][wslot];
      h8 awv1 = *(h8*)&WbV[1][wslot];
#pragma unroll
      for (int mt = 0; mt < 4; ++mt) {
        const f4 z = (f4){0.f, 0.f, 0.f, 0.f};
        f4 a = accK[nt][mt];
        a = MFMA16(awk0, bx[mt][0], a);
        f4 t1 = MFMA16(awk0, bx[mt][1], z);
        t1 = MFMA16(awk1, bx[mt][0], t1);
        accK[nt][mt] = a + t1 * 4.8828125e-4f;

        f4 b = accV[nt][mt];
        b = MFMA16(awv0, bx[mt][0], b);
        f4 t2 = MFMA16(awv0, bx[mt][1], z);
        t2 = MFMA16(awv1, bx[mt][0], t2);
        accV[nt][mt] = b + t2 * 4.8828125e-4f;
      }
    }
  }
#pragma unroll
  for (int nt = 0; nt < 2; ++nt)
#pragma unroll
    for (int mt = 0; mt < 4; ++mt) {
      int m = m0 + wm * 64 + mt * 16 + ln;
      int n = n0 + wn * 32 + nt * 16 + gq * 4;
      int b = m >> 12, l = m & 4095, hh = n >> 6, d = n & 63;
      size_t o = (((size_t)(b * 16 + hh)) * 4096 + l) * 64 + d;
      f4 rk = accK[nt][mt] + *(const f4*)(bk + n);
      f4 rv = accV[nt][mt] + *(const f4*)(bv + n);
      h4 kh, kl, vh, vl;
#pragma unroll
      for (int j = 0; j < 4; ++j) {
        _Float16 p, q;
        split2(rk[j], &p, &q); kh[j] = p; kl[j] = q;
        split2(rv[j], &p, &q); vh[j] = p; vl[j] = q;
      }
      *(h4*)(Kh + o) = kh;
      *(h4*)(Kl + o) = kl;
      *(h4*)(Vh + o) = vh;
      *(h4*)(Vl + o) = vl;
    }
}

// ---------------------------------------------------------------------------
// init: cent0 = Q[:,:, :256, :] stored as split3; fused cnorm.
// (Cqg kept for update's empty-cluster reconstruction fidelity.)
// ---------------------------------------------------------------------------
__global__ __launch_bounds__(256) void init_cent_fused(const float* __restrict__ Q,
                                                       float* __restrict__ cnorm,
                                                       _Float16* __restrict__ Chg,
                                                       _Float16* __restrict__ Clg,
                                                       _Float16* __restrict__ Cqg) {
  const int gid = blockIdx.x * 4 + (threadIdx.x >> 6);  // bh*256+c
  const int bh = gid >> 8, c = gid & 255;
  const int lane = threadIdx.x & 63;
  float v = Q[((size_t)bh * 4096 + c) * 64 + lane];
  size_t ci = (size_t)gid * 64 + lane;
  _Float16 a, b, q;
  split3(v, &a, &b, &q);
  Chg[ci] = a; Clg[ci] = b; Cqg[ci] = q;
  float ss = v * v;
#pragma unroll
  for (int off = 1; off < 64; off <<= 1) ss += __shfl_xor(ss, off, 64);
  if (lane == 0) cnorm[gid] = ss;
}

// ---------------------------------------------------------------------------
// MFMA assign, 3-term distances, rt=4, grid 512, LDS-staged centroids
// (r17/r21-proven best; r22 showed LDS-free direct-global B-frags are
// 128B-stride uncoalesced and regress badly).
// ---------------------------------------------------------------------------
__global__ __launch_bounds__(256) void assign_mfma(const _Float16* __restrict__ Qh,
                                                   const _Float16* __restrict__ Ql,
                                                   const _Float16* __restrict__ Chg,
                                                   const _Float16* __restrict__ Clg,
                                                   const float* __restrict__ cnorm,
                                                   int* __restrict__ assign,
                                                   unsigned* __restrict__ mask) {
  __shared__ _Float16 CS0[8320], CS1[8320];  // 8 slabs x 1040
  __shared__ float cn[128];
  const int t = threadIdx.x;
  const int wave = t >> 6, lane = t & 63;
  const int bh = blockIdx.x & 31, lch = blockIdx.x >> 5;  // lch 0..15
  const int l0 = lch * 256;
  const int gq = lane >> 4, ln = lane & 15;

  // A-frags: this wave's 64 Q rows (pure loads)
  h8 ah[4][2], al[4][2];
#pragma unroll
  for (int rt = 0; rt < 4; ++rt)
#pragma unroll
    for (int ks = 0; ks < 2; ++ks) {
      size_t off =
          ((size_t)bh * 4096 + l0 + wave * 64 + rt * 16 + ln) * 64 + ks * 32 + gq * 8;
      ah[rt][ks] = *(const h8*)(Qh + off);
      al[rt][ks] = *(const h8*)(Ql + off);
    }

  float bestv[4][4];
  int bestc[4][4];
#pragma unroll
  for (int rt = 0; rt < 4; ++rt)
#pragma unroll
    for (int j = 0; j < 4; ++j) { bestv[rt][j] = 3.4e38f; bestc[rt][j] = 0; }

  for (int half = 0; half < 2; ++half) {
    __syncthreads();
#pragma unroll
    for (int i = 0; i < 4; ++i) {
      int gid = t * 4 + i;
      int c = gid >> 3, g = gid & 7;
      size_t src = ((size_t)(bh * 256 + half * 128 + c)) * 64 + g * 8;
      int dst = g * 1040 + c * 8;
      *(h8*)&CS0[dst] = *(const h8*)(Chg + src);
      *(h8*)&CS1[dst] = *(const h8*)(Clg + src);
    }
    if (t < 128) cn[t] = cnorm[bh * 256 + half * 128 + t];
    __syncthreads();

#pragma unroll
    for (int ct = 0; ct < 8; ++ct) {
      const f4 z = (f4){0.f, 0.f, 0.f, 0.f};
      f4 a0[4] = {z, z, z, z}, a1[4] = {z, z, z, z};
#pragma unroll
      for (int ks = 0; ks < 2; ++ks) {
        int bslot = (ks * 4 + gq) * 1040 + (ct * 16 + ln) * 8;
        h8 bh_ = *(h8*)&CS0[bslot];
        h8 bl_ = *(h8*)&CS1[bslot];
#pragma unroll
        for (int rt = 0; rt < 4; ++rt) {
          a0[rt] = MFMA16(ah[rt][ks], bh_, a0[rt]);
          a1[rt] = MFMA16(ah[rt][ks], bl_, a1[rt]);
          a1[rt] = MFMA16(al[rt][ks], bh_, a1[rt]);
        }
      }
      float cnv = cn[ct * 16 + ln];
      int cbase = half * 128 + ct * 16 + ln;
#pragma unroll
      for (int rt = 0; rt < 4; ++rt) {
        f4 dot = a0[rt] + a1[rt] * 4.8828125e-4f;
#pragma unroll
        for (int j = 0; j < 4; ++j) {
          float dist = fmaf(-2.f, dot[j], cnv);
          if (dist < bestv[rt][j]) { bestv[rt][j] = dist; bestc[rt][j] = cbase; }
        }
      }
    }
  }
#pragma unroll
  for (int rt = 0; rt < 4; ++rt)
#pragma unroll
    for (int j = 0; j < 4; ++j) {
      float v = bestv[rt][j];
      int c = bestc[rt][j];
#pragma unroll
      for (int off = 1; off < 16; off <<= 1) {
        float ov = __shfl_xor(v, off, 64);
        int oc = __shfl_xor(c, off, 64);
        if (ov < v || (ov == v && oc < c)) { v = ov; c = oc; }
      }
      if (ln == 0) {
        int l = l0 + wave * 64 + rt * 16 + gq * 4 + j;
        assign[(size_t)bh * 4096 + l] = c;
        atomicOr(&mask[(((size_t)bh * 256 + c) << 7) + (l >> 5)], 1u << (l & 31));
      }
    }
}

// ---------------------------------------------------------------------------
// centroid update, 4-way wave-parallel scan (r18-proven). Clears mask;
// fused cnorm + split3. Reads fp32 Q.
// ---------------------------------------------------------------------------
__global__ __launch_bounds__(256) void update4_kernel(const float* __restrict__ Q,
                                                      unsigned* __restrict__ mask,
                                                      float* __restrict__ cnorm,
                                                      _Float16* __restrict__ Chg,
                                                      _Float16* __restrict__ Clg,
                                                      _Float16* __restrict__ Cqg) {
  const int gid = blockIdx.x;           // bh*256+c
  const int bh = gid >> 8;
  const int t = threadIdx.x;
  const int wave = t >> 6, lane = t & 63;
  __shared__ unsigned w[128];
  __shared__ float psum[4][64];
  __shared__ int pcnt[4];
  unsigned* mp = mask + ((size_t)gid << 7);
  if (t < 128) {
    w[t] = mp[t];
    mp[t] = 0u;  // self-restoring for next iteration / next call
  }
  __syncthreads();
  float sum = 0.f;
  int cnt = 0;
  const float* qb = Q + (size_t)bh * 4096 * 64 + lane;
  const int i0 = wave * 32;
  for (int i = i0; i < i0 + 32; ++i) {
    unsigned u = w[i];
    while (u) {  // wave-uniform
      int b = __ffs(u) - 1;
      u &= u - 1;
      int l = i * 32 + b;
      sum += qb[(size_t)l * 64];
      ++cnt;
    }
  }
  psum[wave][lane] = sum;
  if (lane == 0) pcnt[wave] = cnt;
  __syncthreads();
  if (wave == 0) {
    int total = (pcnt[0] + pcnt[1]) + (pcnt[2] + pcnt[3]);
    size_t ci = (size_t)gid * 64 + lane;
    float v;
    if (total) {
      float s = (psum[0][lane] + psum[1][lane]) + (psum[2][lane] + psum[3][lane]);
      v = s / (float)total;
    } else {
      v = (float)Chg[ci] + (float)Clg[ci] * 4.8828125e-4f +
          (float)Cqg[ci] * 2.384185791015625e-7f;
    }
    _Float16 a, b2, q;
    split3(v, &a, &b2, &q);
    Chg[ci] = a; Clg[ci] = b2; Cqg[ci] = q;
    float ss = v * v;
#pragma unroll
    for (int off = 1; off < 64; off <<= 1) ss += __shfl_xor(ss, off, 64);
    if (lane == 0) cnorm[gid] = ss;
  }
}

// ---------------------------------------------------------------------------
// MFMA flash attention. 16 uniform chunks of 4x64 l-tiles; grid 512.
// ---------------------------------------------------------------------------
#define NCH 16
__global__ __launch_bounds__(256) void attn_mfma(const _Float16* __restrict__ Kh,
                                                 const _Float16* __restrict__ Kl,
                                                 const _Float16* __restrict__ Vh,
                                                 const _Float16* __restrict__ Vl,
                                                 const _Float16* __restrict__ Chg,
                                                 const _Float16* __restrict__ Clg,
                                                 float* __restrict__ pacc,
                                                 float* __restrict__ pml) {
  __shared__ _Float16 KhS[4160], KlS[4160];    // 8 slabs x 520
  __shared__ _Float16 VhT[64 * 72], VlT[64 * 72];
  __shared__ _Float16 Ph[4][16 * 72], Pl[4][16 * 72];
  const int bh = blockIdx.x & 31, ch = blockIdx.x >> 5;  // ch 0..15
  const int t = threadIdx.x;
  const int wave = t >> 6, lane = t & 63, gq = lane >> 4, ln = lane & 15;

  h8 cah[4][2], cal[4][2];
#pragma unroll
  for (int cb = 0; cb < 4; ++cb)
#pragma unroll
    for (int ks = 0; ks < 2; ++ks) {
      size_t off = ((size_t)bh * 256 + wave * 64 + cb * 16 + ln) * 64 + ks * 32 + gq * 8;
      cah[cb][ks] = *(const h8*)(Chg + off);
      cal[cb][ks] = *(const h8*)(Clg + off);
    }

  f4 mr[4], ls[4], acc[4][4];
#pragma unroll
  for (int cb = 0; cb < 4; ++cb) {
    mr[cb] = (f4){-3.0e38f, -3.0e38f, -3.0e38f, -3.0e38f};
    ls[cb] = (f4){0.f, 0.f, 0.f, 0.f};
#pragma unroll
    for (int dt = 0; dt < 4; ++dt) acc[cb][dt] = (f4){0.f, 0.f, 0.f, 0.f};
  }

  for (int lt = 0; lt < 4; ++lt) {
    const int l0 = (ch * 4 + lt) * 64;
    __syncthreads();
#pragma unroll
    for (int i = 0; i < 2; ++i) {  // stage K (h8 copies) + V (transposed)
      int gid = t * 2 + i;
      int l = gid >> 3, g = gid & 7;
      size_t src = ((size_t)bh * 4096 + l0 + l) * 64 + g * 8;
      int dst = g * 520 + l * 8;
      *(h8*)&KhS[dst] = *(const h8*)(Kh + src);
      *(h8*)&KlS[dst] = *(const h8*)(Kl + src);
      h8 vh = *(const h8*)(Vh + src);
      h8 vl = *(const h8*)(Vl + src);
#pragma unroll
      for (int j = 0; j < 8; ++j) {
        VhT[(g * 8 + j) * 72 + l] = vh[j];
        VlT[(g * 8 + j) * 72 + l] = vl[j];
      }
    }
    __syncthreads();

#pragma unroll
    for (int cb = 0; cb < 4; ++cb) {
      // ---- QK^T: S rows c (=gq*4+j), cols l (=st*16+ln)
      f4 s[4];
#pragma unroll
      for (int st = 0; st < 4; ++st) {
        const f4 z = (f4){0.f, 0.f, 0.f, 0.f};
        f4 a0 = z, a1 = z;
#pragma unroll
        for (int ks = 0; ks < 2; ++ks) {
          int bslot = (ks * 4 + gq) * 520 + (st * 16 + ln) * 8;
          h8 kbh = *(h8*)&KhS[bslot];
          h8 kbl = *(h8*)&KlS[bslot];
          a0 = MFMA16(cah[cb][ks], kbh, a0);
          a1 = MFMA16(cah[cb][ks], kbl, a1);
          a1 = MFMA16(cal[cb][ks], kbh, a1);
        }
        s[st] = (a0 + a1 * 4.8828125e-4f) * 0.125f;
      }
      // ---- online softmax (per c = gq*4+j)
      f4 ml;
#pragma unroll
      for (int j = 0; j < 4; ++j)
        ml[j] = fmaxf(fmaxf(s[0][j], s[1][j]), fmaxf(s[2][j], s[3][j]));
#pragma unroll
      for (int off = 1; off < 16; off <<= 1)
#pragma unroll
        for (int j = 0; j < 4; ++j) ml[j] = fmaxf(ml[j], __shfl_xor(ml[j], off, 64));
      f4 mn, corr;
#pragma unroll
      for (int j = 0; j < 4; ++j) {
        mn[j] = fmaxf(mr[cb][j], ml[j]);
        corr[j] = __expf(mr[cb][j] - mn[j]);
      }
      f4 psum = (f4){0.f, 0.f, 0.f, 0.f};
#pragma unroll
      for (int st = 0; st < 4; ++st) {
#pragma unroll
        for (int j = 0; j < 4; ++j) {
          float p = __expf(s[st][j] - mn[j]);
          psum[j] += p;
          _Float16 a, b;
          split2(p, &a, &b);
          Ph[wave][(gq * 4 + j) * 72 + st * 16 + ln] = a;
          Pl[wave][(gq * 4 + j) * 72 + st * 16 + ln] = b;
        }
      }
#pragma unroll
      for (int off = 1; off < 16; off <<= 1)
#pragma unroll
        for (int j = 0; j < 4; ++j) psum[j] += __shfl_xor(psum[j], off, 64);
      ls[cb] = ls[cb] * corr + psum;
      mr[cb] = mn;
#pragma unroll
      for (int dt = 0; dt < 4; ++dt) acc[cb][dt] *= corr;
      // ---- PV (same-wave LDS handoff)
#pragma unroll
      for (int ks = 0; ks < 2; ++ks) {
        h8 pah = *(h8*)&Ph[wave][ln * 72 + ks * 32 + gq * 8];
        h8 pal = *(h8*)&Pl[wave][ln * 72 + ks * 32 + gq * 8];
#pragma unroll
        for (int dt = 0; dt < 4; ++dt) {
          int vslot = (dt * 16 + ln) * 72 + ks * 32 + gq * 8;
          h8 vbh = *(h8*)&VhT[vslot];
          h8 vbl = *(h8*)&VlT[vslot];
          acc[cb][dt] = MFMA16(pah, vbh, acc[cb][dt]);
          const f4 z = (f4){0.f, 0.f, 0.f, 0.f};
          f4 t1 = MFMA16(pah, vbl, z);
          t1 = MFMA16(pal, vbh, t1);
          acc[cb][dt] += t1 * 4.8828125e-4f;
        }
      }
    }
  }
  // ---- write partials
#pragma unroll
  for (int cb = 0; cb < 4; ++cb) {
    int crow = wave * 64 + cb * 16 + gq * 4;
#pragma unroll
    for (int dt = 0; dt < 4; ++dt)
#pragma unroll
      for (int j = 0; j < 4; ++j)
        pacc[((size_t)ch * 8192 + bh * 256 + crow + j) * 64 + dt * 16 + ln] = acc[cb][dt][j];
    if (ln == 0) {
#pragma unroll
      for (int j = 0; j < 4; ++j) {
        size_t r = (size_t)ch * 8192 + bh * 256 + crow + j;
        pml[r * 2 + 0] = mr[cb][j];
        pml[r * 2 + 1] = ls[cb][j];
      }
    }
  }
}

// ---------------------------------------------------------------------------
// merge 16 chunk-partials -> Oc[bh*256+c][64]
// ---------------------------------------------------------------------------
__global__ __launch_bounds__(256) void merge_kernel(const float* __restrict__ pacc,
                                                    const float* __restrict__ pml,
                                                    float* __restrict__ Oc) {
  const int row = blockIdx.x * 4 + (threadIdx.x >> 6);
  const int lane = threadIdx.x & 63;
  float M = -3.0e38f;
#pragma unroll
  for (int q = 0; q < NCH; ++q) M = fmaxf(M, pml[((size_t)q * 8192 + row) * 2]);
  float S = 0.f, o = 0.f;
#pragma unroll
  for (int q = 0; q < NCH; ++q) {
    size_t r = (size_t)q * 8192 + row;
    float w = __expf(pml[r * 2] - M);
    S = fmaf(w, pml[r * 2 + 1], S);
    o = fmaf(w, pacc[r * 64 + lane], o);
  }
  Oc[(size_t)row * 64 + lane] = o / S;
}

// ---------------------------------------------------------------------------
// gather + split2: Oh/Ol[b][l][h*64+d] = split2(Oc[b][h][assign[b][h][l]][d])
// ---------------------------------------------------------------------------
__global__ void gather_kernel(const float* __restrict__ Oc,
                              const int* __restrict__ assign,
                              _Float16* __restrict__ Oh,
                              _Float16* __restrict__ Ol) {
  size_t idx = (size_t)blockIdx.x * 256 + threadIdx.x;
  int d4 = (int)(idx & 15) * 4;
  size_t rest = idx >> 4;
  int h = (int)(rest & 15);
  size_t bl = rest >> 4;
  int b = (int)(bl >> 12);
  int l = (int)(bl & 4095);
  int bh = b * 16 + h;
  int a = assign[(size_t)bh * 4096 + l];
  float4 v = *(const float4*)(Oc + (((size_t)bh * 256 + a) * 64 + d4));
  float xs[4] = {v.x, v.y, v.z, v.w};
  h4 vh, vl;
#pragma unroll
  for (int j = 0; j < 4; ++j) {
    _Float16 p, q;
    split2(xs[j], &p, &q);
    vh[j] = p; vl[j] = q;
  }
  size_t o = bl * 1024 + (size_t)h * 64 + d4;
  *(h4*)(Oh + o) = vh;
  *(h4*)(Ol + o) = vl;
}

// ---------------------------------------------------------------------------
extern "C" void kernel_launch(void* const* d_in, const int* in_sizes, int n_in,
                              void* d_out, int out_size, void* d_ws, size_t ws_size,
                              hipStream_t stream) {
  const float* X  = (const float*)d_in[0];
  const float* Wq = (const float*)d_in[3];
  const float* bq = (const float*)d_in[4];
  const float* Wk = (const float*)d_in[5];
  const float* bk = (const float*)d_in[6];
  const float* Wv = (const float*)d_in[7];
  const float* bv = (const float*)d_in[8];
  const float* Wo = (const float*)d_in[9];
  const float* bo = (const float*)d_in[10];
  float* out = (float*)d_out;

  // ---- Workspace (floats), total 26,353,664 == proven budget (r19 layout).
  // R1 [0, 8,388,608):  A-B: Q fp32 | C: Wthk/Wtlk/Wthv/Wtlv | D: pacc
  // R2 [8,388,608, 16,777,216): A: WthQ/WtlQ@0 + Qh@+1,048,576 (A-B) |
  //                             C-D: Kh/Kl | E: Oh/Ol
  // R3 [16,777,216, 25,165,824): A-B: Ql@0 | B: mask@+4,194,304 | C-D: Vh/Vl |
  //                              D-E: Oc@0 | E: Wth3/Wtl3@+524,288
  // R4 [25,165,824, 26,353,664): cnorm | assign | Chg | Clg | Cqg | pml
  // d_out (8,388,608 fl = 16,777,216 halfs): A-C: Xh/Xl | E: final output.
  float* W0 = (float*)d_ws;
  float* R1 = W0;
  float* R2 = W0 + 8388608;
  float* R3 = W0 + 16777216;
  float* R4 = W0 + 25165824;

  _Float16* Xh = (_Float16*)out;                  // 8,388,608 halfs
  _Float16* Xl = (_Float16*)out + 8388608;        // 8,388,608 halfs

  float* Q = R1;
  _Float16* WthQ = (_Float16*)R2;
  _Float16* WtlQ = (_Float16*)(R2 + 524288);
  _Float16* Qh = (_Float16*)(R2 + 1048576);       // A-B (written by MODE-4 gemm)
  _Float16* Ql = (_Float16*)R3;                   // A-B

  float* cnorm = R4;                              // 8,192
  int* assign  = (int*)(R4 + 8192);               // 131,072
  _Float16* Chg = (_Float16*)(R4 + 139264);       // 524,288 halfs
  _Float16* Clg = (_Float16*)(R4 + 401408);
  _Float16* Cqg = (_Float16*)(R4 + 663552);
  float* pml    = R4 + 925696;                    // 16*8192*2 = 262,144
  unsigned* mask = (unsigned*)(R3 + 4194304);     // 1,048,576 words (phase B)

  _Float16* Wthk = (_Float16*)R1;                 // phase C (Q dead)
  _Float16* Wtlk = (_Float16*)(R1 + 524288);
  _Float16* Wthv = (_Float16*)(R1 + 1048576);
  _Float16* Wtlv = (_Float16*)(R1 + 1572864);
  _Float16* Kh = (_Float16*)R2;                   // C -> D (WthQ/Qh dead)
  _Float16* Kl = (_Float16*)(R2 + 4194304);
  _Float16* Vh = (_Float16*)R3;                   // C -> D (Ql, mask dead)
  _Float16* Vl = (_Float16*)(R3 + 4194304);

  float* pacc = R1;                               // D
  float* Oc   = R3;                               // D -> E (Vh dead)

  _Float16* Oh = (_Float16*)R2;                   // E (Kh/Kl dead)
  _Float16* Ol = (_Float16*)(R2 + 4194304);
  _Float16* Wth3 = (_Float16*)(R3 + 524288);      // E (after Oc)
  _Float16* Wtl3 = (_Float16*)(R3 + 1048576);

  dim3 tgrid(32, 32);
  dim3 ggrid(64, 16);                              // 128x64 tiles -> 1024 blocks
  size_t smem2 = (size_t)(2 * 4096 + 2 * 2048) * sizeof(_Float16);  // 24,576 B

  // Phase A: pre-split X (2-way); Q projection (SPLITS=2, MODE 4: also emits
  // Qh/Ql split2 halves in the epilogue -> xsplit2(Q) pass eliminated).
  xsplit2_kernel<<<8192, 256, 0, stream>>>(X, Xh, Xl);
  tsplit_kernel<<<tgrid, 256, 0, stream>>>(Wq, WthQ, WtlQ, nullptr);
  gemm_pre<2, 4><<<ggrid, 256, smem2, stream>>>(Xh, Xl, nullptr, WthQ, WtlQ, nullptr,
                                                bq, Q, Qh, Ql);

  // Phase B: k-means (11 assign/update rounds); assign rt=4; update 4-wave
  init_cent_fused<<<2048, 256, 0, stream>>>(Q, cnorm, Chg, Clg, Cqg);
  hipMemsetAsync(mask, 0, 1048576 * sizeof(unsigned), stream);
  for (int it = 0; it < 11; ++it) {
    assign_mfma<<<512, 256, 0, stream>>>(Qh, Ql, Chg, Clg, cnorm, assign, mask);
    update4_kernel<<<8192, 256, 0, stream>>>(Q, mask, cnorm, Chg, Clg, Cqg);
  }

  // Phase C: fused K+V projection (XCD-swizzled); single fused W-transpose.
  tsplit_kv_kernel<<<tgrid, 256, 0, stream>>>(Wk, Wv, Wthk, Wtlk, Wthv, Wtlv);
  gemm_kv<<<1024, 256, 0, stream>>>(Xh, Xl, Wthk, Wtlk, Wthv, Wtlv, bk, bv,
                                    Kh, Kl, Vh, Vl);

  // Phase D: clustered attention (16 uniform L-chunks) + merge
  attn_mfma<<<512, 256, 0, stream>>>(Kh, Kl, Vh, Vl, Chg, Clg, pacc, pml);
  merge_kernel<<<2048, 256, 0, stream>>>(pacc, pml, Oc);

  // Phase E: gather (emits split2) + output projection
  gather_kernel<<<8192, 256, 0, stream>>>(Oc, assign, Oh, Ol);
  tsplit_kernel<<<tgrid, 256, 0, stream>>>(Wo, Wth3, Wtl3, nullptr);
  gemm_pre<2, 0><<<ggrid, 256, smem2, stream>>>(Oh, Ol, nullptr, Wth3, Wtl3, nullptr, bo,
                                                out, nullptr, nullptr);
}